// Round 4
// baseline (384.410 us; speedup 1.0000x reference)
//
#include <hip/hip_runtime.h>

#define NN 10000    // nodes
#define RR 100      // relations
#define EE 5000     // edges per relation
#define D0 2048
#define D1 128
#define D2 64
#define D3 20
#define NE (RR*EE)  // 500000 edges total

using short8  = __attribute__((ext_vector_type(8))) short;
using float4e = __attribute__((ext_vector_type(4))) float;

__device__ __forceinline__ unsigned short f2bf(float f) {
  unsigned int u = __float_as_uint(f);
  unsigned int r = u + 0x7fffu + ((u >> 16) & 1u);   // RNE
  return (unsigned short)(r >> 16);
}
__device__ __forceinline__ float bf2f(unsigned short u) {
  return __uint_as_float(((unsigned int)u) << 16);
}
__device__ __forceinline__ unsigned int pk2(float lo, float hi) {
  return ((unsigned int)f2bf(hi) << 16) | (unsigned int)f2bf(lo);
}

// bf16x8 MFMA on uint4-typed fragments
__device__ __forceinline__ float4e bmm(uint4 a, uint4 b, float4e c) {
  return __builtin_amdgcn_mfma_f32_16x16x32_bf16(
      __builtin_bit_cast(short8, a), __builtin_bit_cast(short8, b), c, 0, 0, 0);
}

// ---------------------------------------------------------------------------
// fused prep: deg histogram + all three weight->bf16 fragment-layout packs
// frag element (for a 16-col tile nt): k = c*32 + (lane>>4)*8 + j,
//                                      n = nt*16 + (lane&15)
// ---------------------------------------------------------------------------
#define W0_SZ 262144   // drug_w frags: c 0..63, nt 0..7
#define W1_SZ 73728    // Wc1 frags:    c 0..35, nt 0..3
#define W2_SZ 18432    // Wc2 frags:    c 0..17, nt 0..1
__global__ void prep_kernel(const int* __restrict__ ei, int* __restrict__ deg,
                            const float* __restrict__ drug_w,
                            unsigned short* __restrict__ Bfw,
                            const float* __restrict__ root1,
                            const float* __restrict__ basis1,
                            unsigned short* __restrict__ Wf1,
                            const float* __restrict__ root2,
                            const float* __restrict__ basis2,
                            unsigned short* __restrict__ Wf2) {
  int gid = blockIdx.x * 256 + threadIdx.x;
  if (gid < NE) {
    int r = gid / EE, e = gid - r * EE;
    int d = ei[r * 2 * EE + EE + e];
    atomicAdd(&deg[r * NN + d], 1);
    return;
  }
  gid -= NE;
  if (gid < W0_SZ) {
    int j = gid & 7, lane = (gid >> 3) & 63, rest = gid >> 9;
    int nt = rest & 7, c = rest >> 3;
    int k = c * 32 + (lane >> 4) * 8 + j;
    int n = nt * 16 + (lane & 15);
    Bfw[gid] = f2bf(drug_w[(size_t)k * 128 + n]);
    return;
  }
  gid -= W0_SZ;
  if (gid < W1_SZ) {
    int j = gid & 7, lane = (gid >> 3) & 63, rest = gid >> 9;
    int nt = rest & 3, c = rest >> 2;
    int k = c * 32 + (lane >> 4) * 8 + j;
    int o = nt * 16 + (lane & 15);
    float v = (k < 128) ? root1[k * 64 + o] : basis1[(k - 128) * 64 + o];
    Wf1[gid] = f2bf(v);
    return;
  }
  gid -= W1_SZ;
  if (gid < W2_SZ) {
    int j = gid & 7, lane = (gid >> 3) & 63, rest = gid >> 9;
    int nt = rest & 1, c = rest >> 1;
    int k = c * 32 + (lane >> 4) * 8 + j;
    int cc = nt * 16 + (lane & 15);
    float v = 0.f;
    if (cc < 20) v = (k < 64) ? root2[k * 20 + cc] : basis2[(k - 64) * 20 + cc];
    Wf2[gid] = f2bf(v);
  }
}

__global__ void cnt_kernel(const int* __restrict__ deg, int* __restrict__ cnt) {
  int n = blockIdx.x * 256 + threadIdx.x;
  if (n >= NN) return;
  int s = 0;
  for (int r = 0; r < RR; r++) s += deg[r * NN + n];
  cnt[n] = s;
}

// ---------------------------------------------------------------------------
// single-pass scan: thread t serially scans nodes [t*10, t*10+10); one
// block-scan of the 1024 thread totals; one barrier phase (vs 10 before).
// ---------------------------------------------------------------------------
__global__ __launch_bounds__(1024) void scan_kernel(const int* __restrict__ cnt,
                                                    int* __restrict__ off,
                                                    int* __restrict__ cur) {
  __shared__ int wsum[16];
  const int tid = threadIdx.x;
  const int wv = tid >> 6, lane = tid & 63;
  const bool act = tid < 1000;
  int loc[10];
  int s = 0;
  if (act) {
#pragma unroll
    for (int i = 0; i < 10; i++) { loc[i] = cnt[tid * 10 + i]; s += loc[i]; }
  }
  int ws = s;
#pragma unroll
  for (int d = 1; d < 64; d <<= 1) {
    int t = __shfl_up(ws, d, 64);
    if (lane >= d) ws += t;
  }
  if (lane == 63) wsum[wv] = ws;
  __syncthreads();
  if (wv == 0) {
    int w = (lane < 16) ? wsum[lane] : 0;
#pragma unroll
    for (int d = 1; d < 16; d <<= 1) {
      int t = __shfl_up(w, d, 64);
      if (lane >= d) w += t;
    }
    if (lane < 16) wsum[lane] = w;
  }
  __syncthreads();
  int excl = (wv ? wsum[wv - 1] : 0) + ws - s;
  if (act) {
    int run = excl;
#pragma unroll
    for (int i = 0; i < 10; i++) {
      off[tid * 10 + i] = run;
      cur[tid * 10 + i] = run;
      run += loc[i];
    }
  }
  if (tid == 1023) off[NN] = excl;   // s==0 for tid>=1000 -> excl == total
}

// rec = (r<<14)|src, esc = 1/max(deg,1)
__global__ void scatter_kernel(const int* __restrict__ ei,
                               const int* __restrict__ deg,
                               int* __restrict__ cur, int* __restrict__ rec,
                               float* __restrict__ esc) {
  int gid = blockIdx.x * 256 + threadIdx.x;
  if (gid >= NE) return;
  int r = gid / EE, e = gid - r * EE;
  int s = ei[r * 2 * EE + e];
  int d = ei[r * 2 * EE + EE + e];
  int p = atomicAdd(&cur[d], 1);
  rec[p] = (r << 14) | s;
  esc[p] = 1.0f / fmaxf((float)deg[r * NN + d], 1.0f);
}

// ---------------------------------------------------------------------------
// gemm0_v5: xb = bf16(x_drug @ drug_w)
// M=32 per block (313 blocks -> full CU coverage), N=128, 4 waves (wave nw:
// cols nw*32..+32). A: coalesced fp32 loads -> bf16 -> XOR-swizzled LDS
// [2][32][128], 2 K-tiles ahead in regs. B: direct frag-layout loads
// (L2-resident), 1 tile ahead. 16 K-tiles of 128; 2 barriers / 2 tiles.
// ---------------------------------------------------------------------------
__global__ __launch_bounds__(256) void gemm0_v5(
    const float* __restrict__ A, const unsigned short* __restrict__ Bfw,
    unsigned short* __restrict__ xb) {
  __shared__ unsigned short As[2][32 * 128];
  const int tid = threadIdx.x;
  const int nw = tid >> 6, lane = tid & 63;
  const int lrow = lane & 15, quad = lane >> 4;
  const int m0 = blockIdx.x * 32;

  // staging: thread covers rows rb+8j (j=0..3), 1 float4 per row (li*16B)
  const int rb = tid >> 5, li = tid & 31;
  int rg[4], wo[4];
#pragma unroll
  for (int j = 0; j < 4; j++) {
    int r = rb + 8 * j;
    int g = m0 + r;
    rg[j] = g < NN ? g : NN - 1;
    wo[j] = r * 128 + (((li >> 1) ^ (r & 15)) & 15) * 8 + (li & 1) * 4;
  }

  const uint4* Bq = (const uint4*)Bfw;
  float4 rAe[4], rAo[4];
  uint4 B0[8], B1[8];
  float4e acc[2][2];
#pragma unroll
  for (int mt = 0; mt < 2; mt++)
#pragma unroll
    for (int i = 0; i < 2; i++) {
      acc[mt][i][0] = 0.f; acc[mt][i][1] = 0.f;
      acc[mt][i][2] = 0.f; acc[mt][i][3] = 0.f;
    }

#define LDA(ra, t)                                                   \
  { int tc = (t) > 15 ? 15 : (t);                                    \
    _Pragma("unroll")                                                \
    for (int j = 0; j < 4; j++)                                      \
      ra[j] = *(const float4*)(A + (size_t)rg[j] * D0 + tc * 128 + li * 4); }
#define LDB(B, t)                                                    \
  { int tc = (t) > 15 ? 15 : (t);                                    \
    _Pragma("unroll")                                                \
    for (int kk = 0; kk < 4; kk++) {                                 \
      B[2 * kk]     = Bq[((tc * 4 + kk) * 8 + 2 * nw) * 64 + lane];  \
      B[2 * kk + 1] = Bq[((tc * 4 + kk) * 8 + 2 * nw + 1) * 64 + lane]; } }
#define STA(buf, ra)                                                 \
  { _Pragma("unroll")                                                \
    for (int j = 0; j < 4; j++) {                                    \
      uint2 u; u.x = pk2(ra[j].x, ra[j].y); u.y = pk2(ra[j].z, ra[j].w); \
      *(uint2*)&As[buf][wo[j]] = u; } }
#define CMP(buf, B)                                                  \
  { _Pragma("unroll")                                                \
    for (int kk = 0; kk < 4; kk++) {                                 \
      _Pragma("unroll")                                              \
      for (int mt = 0; mt < 2; mt++) {                               \
        uint4 af = *(const uint4*)&As[buf][(mt * 16 + lrow) * 128 +  \
                                           (((kk * 4 + quad) ^ lrow) & 15) * 8]; \
        acc[mt][0] = bmm(af, B[2 * kk], acc[mt][0]);                 \
        acc[mt][1] = bmm(af, B[2 * kk + 1], acc[mt][1]); } } }

  LDA(rAe, 0); LDB(B0, 0);
  LDA(rAo, 1);
  STA(0, rAe);
  LDB(B1, 1);
  LDA(rAe, 2);
  __syncthreads();

  for (int t = 0; t < 16; t += 2) {
    STA(1, rAo);
    LDA(rAo, t + 3);
    CMP(0, B0);
    LDB(B0, t + 2);
    __syncthreads();
    STA(0, rAe);
    LDA(rAe, t + 4);
    CMP(1, B1);
    LDB(B1, t + 3);
    __syncthreads();
  }
#undef LDA
#undef LDB
#undef STA
#undef CMP

  const int c0 = nw * 32 + lrow;
#pragma unroll
  for (int mt = 0; mt < 2; mt++) {
#pragma unroll
    for (int j = 0; j < 4; j++) {
      int r = m0 + mt * 16 + quad * 4 + j;
      if (r < NN) {
        xb[(size_t)r * D1 + c0]      = f2bf(acc[mt][0][j]);
        xb[(size_t)r * D1 + c0 + 16] = f2bf(acc[mt][1][j]);
      }
    }
  }
}

// ---------------------------------------------------------------------------
// agg1e: A1b[n, b*128+i] = bf16( sum_{e->n} esc_e*comp1[r_e,b]*x[src_e,i] )
// one wave per node, split into 2 half-waves: half h processes edges
// beg+h, beg+h+2, ... ; lane covers 4 channels (8B loads). Cross-half
// combine via one shfl_xor(32) round at the end.
// ---------------------------------------------------------------------------
__global__ __launch_bounds__(256) void agg1e_kernel(
    const unsigned short* __restrict__ xb, const int* __restrict__ off,
    const int* __restrict__ rec, const float* __restrict__ esc,
    const float* __restrict__ comp, unsigned short* __restrict__ A1b) {
  __shared__ float s_comp[RR * 8];
  const int tid = threadIdx.x;
  for (int i = tid; i < RR * 8; i += 256) s_comp[i] = comp[i];
  __syncthreads();
  const int wv = tid >> 6, lane = tid & 63;
  const int half = lane >> 5, li = lane & 31;
  const int n = blockIdx.x * 4 + wv;
  if (n >= NN) return;
  const int beg = off[n], end = off[n + 1];
  float acc[8][4];
#pragma unroll
  for (int b = 0; b < 8; b++)
#pragma unroll
    for (int k = 0; k < 4; k++) acc[b][k] = 0.f;

  for (int e = beg + half; e < end; e += 2) {
    int rc = rec[e];
    float sc = esc[e];
    uint2 xv = *(const uint2*)&xb[(size_t)(rc & 16383) * D1 + li * 4];
    const float* cb = &s_comp[(rc >> 14) * 8];
    float x0 = sc * __uint_as_float((xv.x & 0xffffu) << 16);
    float x1 = sc * __uint_as_float(xv.x & 0xffff0000u);
    float x2 = sc * __uint_as_float((xv.y & 0xffffu) << 16);
    float x3 = sc * __uint_as_float(xv.y & 0xffff0000u);
#pragma unroll
    for (int b = 0; b < 8; b++) {
      float w = cb[b];
      acc[b][0] += w * x0; acc[b][1] += w * x1;
      acc[b][2] += w * x2; acc[b][3] += w * x3;
    }
  }
  // combine halves
#pragma unroll
  for (int b = 0; b < 8; b++)
#pragma unroll
    for (int k = 0; k < 4; k++) acc[b][k] += __shfl_xor(acc[b][k], 32);
  // half h writes basis 4h..4h+3 (static acc indices via cndmask)
#pragma unroll
  for (int bb = 0; bb < 4; bb++) {
    float v0 = half ? acc[bb + 4][0] : acc[bb][0];
    float v1 = half ? acc[bb + 4][1] : acc[bb][1];
    float v2 = half ? acc[bb + 4][2] : acc[bb][2];
    float v3 = half ? acc[bb + 4][3] : acc[bb][3];
    ushort4 o;
    o.x = f2bf(v0); o.y = f2bf(v1); o.z = f2bf(v2); o.w = f2bf(v3);
    *(ushort4*)&A1b[(size_t)n * 1024 + (half * 4 + bb) * 128 + li * 4] = o;
  }
}

// ---------------------------------------------------------------------------
// agg2e: 4 quarter-waves, 4 edges per iteration; lane covers 4 of 64 ch.
// Cross-quarter combine via shfl_xor(16)+shfl_xor(32).
// ---------------------------------------------------------------------------
__global__ __launch_bounds__(256) void agg2e_kernel(
    const unsigned short* __restrict__ hb, const int* __restrict__ off,
    const int* __restrict__ rec, const float* __restrict__ esc,
    const float* __restrict__ comp, unsigned short* __restrict__ A2b) {
  __shared__ float s_comp[RR * 8];
  const int tid = threadIdx.x;
  for (int i = tid; i < RR * 8; i += 256) s_comp[i] = comp[i];
  __syncthreads();
  const int wv = tid >> 6, lane = tid & 63;
  const int qt = lane >> 4, li = lane & 15;
  const int q0 = qt & 1, q1 = qt >> 1;
  const int n = blockIdx.x * 4 + wv;
  if (n >= NN) return;
  const int beg = off[n], end = off[n + 1];
  float acc[8][4];
#pragma unroll
  for (int b = 0; b < 8; b++)
#pragma unroll
    for (int k = 0; k < 4; k++) acc[b][k] = 0.f;

  for (int e = beg + qt; e < end; e += 4) {
    int rc = rec[e];
    float sc = esc[e];
    uint2 hv = *(const uint2*)&hb[(size_t)(rc & 16383) * D2 + li * 4];
    const float* cb = &s_comp[(rc >> 14) * 8];
    float h0 = sc * __uint_as_float((hv.x & 0xffffu) << 16);
    float h1 = sc * __uint_as_float(hv.x & 0xffff0000u);
    float h2 = sc * __uint_as_float((hv.y & 0xffffu) << 16);
    float h3 = sc * __uint_as_float(hv.y & 0xffff0000u);
#pragma unroll
    for (int b = 0; b < 8; b++) {
      float w = cb[b];
      acc[b][0] += w * h0; acc[b][1] += w * h1;
      acc[b][2] += w * h2; acc[b][3] += w * h3;
    }
  }
  // combine quarters
#pragma unroll
  for (int b = 0; b < 8; b++)
#pragma unroll
    for (int k = 0; k < 4; k++) {
      acc[b][k] += __shfl_xor(acc[b][k], 16);
      acc[b][k] += __shfl_xor(acc[b][k], 32);
    }
  // quarter q writes basis 2q, 2q+1 (static acc indices)
#pragma unroll
  for (int bb = 0; bb < 2; bb++) {
    float v[4];
#pragma unroll
    for (int k = 0; k < 4; k++) {
      float a0 = q0 ? acc[2 + bb][k] : acc[bb][k];
      float a1 = q0 ? acc[6 + bb][k] : acc[4 + bb][k];
      v[k] = q1 ? a1 : a0;
    }
    ushort4 o;
    o.x = f2bf(v[0]); o.y = f2bf(v[1]); o.z = f2bf(v[2]); o.w = f2bf(v[3]);
    *(ushort4*)&A2b[(size_t)n * 512 + (qt * 2 + bb) * 64 + li * 4] = o;
  }
}

// ---------------------------------------------------------------------------
// hlayer_v4: hb = bf16(relu([xb|A1b](K=1152) @ Wc1 + bias1))
// M=32 (313 blocks), N=64, 4 waves. A staged coalesced bf16 -> swizzled LDS;
// 9 K-tiles of 128. B direct frag-layout. (unchanged)
// ---------------------------------------------------------------------------
__global__ __launch_bounds__(256) void hlayer_v4(
    const unsigned short* __restrict__ xb, const unsigned short* __restrict__ A1b,
    const unsigned short* __restrict__ Wf, const float* __restrict__ bias1,
    unsigned short* __restrict__ hb) {
  __shared__ unsigned short Hs[2][32 * 128];
  const int tid = threadIdx.x;
  const int wv = tid >> 6, lane = tid & 63;
  const int lrow = lane & 15, quad = lane >> 4;
  const int m0 = blockIdx.x * 32;
  const int mt = wv >> 1, nb = (wv & 1) * 2;

  int rgr[2], su4[2], sph[2];
#pragma unroll
  for (int p = 0; p < 2; p++) {
    int idx = tid + p * 256;
    int r = idx >> 4, u = idx & 15;
    int g = m0 + r;
    rgr[p] = g < NN ? g : NN - 1;
    su4[p] = u;
    sph[p] = r * 128 + ((u ^ (r & 15)) & 15) * 8;
  }

  const uint4* Bq = (const uint4*)Wf;
  uint4 rAe[2], rAo[2];
  uint4 B0[8], B1[8];
  float4e acc[2];
#pragma unroll
  for (int i = 0; i < 2; i++) {
    acc[i][0] = 0.f; acc[i][1] = 0.f; acc[i][2] = 0.f; acc[i][3] = 0.f;
  }

#define H_LDA(ra, t)                                                       \
  { int tc = (t) > 8 ? 8 : (t);                                            \
    _Pragma("unroll")                                                      \
    for (int p = 0; p < 2; p++) {                                          \
      const unsigned short* sp = (tc == 0)                                 \
          ? (xb + (size_t)rgr[p] * D1 + su4[p] * 8)                        \
          : (A1b + (size_t)rgr[p] * 1024 + (tc - 1) * 128 + su4[p] * 8);   \
      ra[p] = *(const uint4*)sp; } }
#define H_LDB(B, t)                                                        \
  { int tc = (t) > 8 ? 8 : (t);                                            \
    _Pragma("unroll")                                                      \
    for (int kk = 0; kk < 4; kk++) {                                       \
      int c = tc * 4 + kk;                                                 \
      B[2 * kk]     = Bq[(c * 4 + nb) * 64 + lane];                        \
      B[2 * kk + 1] = Bq[(c * 4 + nb + 1) * 64 + lane]; } }
#define H_STA(buf, ra)                                                     \
  { _Pragma("unroll")                                                      \
    for (int p = 0; p < 2; p++) *(uint4*)&Hs[buf][sph[p]] = ra[p]; }
#define H_CMP(buf, B)                                                      \
  { _Pragma("unroll")                                                      \
    for (int kk = 0; kk < 4; kk++) {                                       \
      uint4 af = *(const uint4*)&Hs[buf][(mt * 16 + lrow) * 128 +          \
                                         (((kk * 4 + quad) ^ lrow) & 15) * 8]; \
      acc[0] = bmm(af, B[2 * kk], acc[0]);                                 \
      acc[1] = bmm(af, B[2 * kk + 1], acc[1]); } }

  H_LDA(rAe, 0); H_LDB(B0, 0);
  H_LDA(rAo, 1);
  H_STA(0, rAe);
  H_LDB(B1, 1);
  H_LDA(rAe, 2);
  __syncthreads();

  for (int t = 0; t < 8; t += 2) {
    H_STA(1, rAo);
    H_LDA(rAo, t + 3);
    H_CMP(0, B0);
    H_LDB(B0, t + 2);
    __syncthreads();
    H_STA(0, rAe);
    H_LDA(rAe, t + 4);
    H_CMP(1, B1);
    H_LDB(B1, t + 3);
    __syncthreads();
  }
  H_CMP(0, B0);                                   // tile 8
#undef H_LDA
#undef H_LDB
#undef H_STA
#undef H_CMP

#pragma unroll
  for (int ntl = 0; ntl < 2; ntl++) {
    int col = (nb + ntl) * 16 + lrow;
    float bv = bias1[col];
#pragma unroll
    for (int j = 0; j < 4; j++) {
      int r = m0 + mt * 16 + quad * 4 + j;
      if (r < NN)
        hb[(size_t)r * D2 + col] = f2bf(fmaxf(acc[ntl][j] + bv, 0.f));
    }
  }
}

// ---------------------------------------------------------------------------
// out_v4: out = [hb|A2b](K=576) @ Wc2 + bias2 (unchanged)
// ---------------------------------------------------------------------------
__global__ __launch_bounds__(128) void out_v4(
    const unsigned short* __restrict__ hb, const unsigned short* __restrict__ A2b,
    const unsigned short* __restrict__ Wf, const float* __restrict__ bias2,
    float* __restrict__ out) {
  __shared__ unsigned short Os[2][32 * 64];
  const int tid = threadIdx.x;
  const int wv = tid >> 6, lane = tid & 63;
  const int lrow = lane & 15, quad = lane >> 4;
  const int m0 = blockIdx.x * 32;

  int rgr[2], su4[2], sph[2];
#pragma unroll
  for (int p = 0; p < 2; p++) {
    int idx = tid + p * 128;
    int r = idx >> 3, u = idx & 7;
    int g = m0 + r;
    rgr[p] = g < NN ? g : NN - 1;
    su4[p] = u;
    sph[p] = r * 64 + ((u ^ (r & 7)) & 7) * 8;
  }

  const uint4* Bq = (const uint4*)Wf;
  uint4 rAe[2], rAo[2];
  uint4 B0[4], B1[4];
  float4e acc[2];
#pragma unroll
  for (int i = 0; i < 2; i++) {
    acc[i][0] = 0.f; acc[i][1] = 0.f; acc[i][2] = 0.f; acc[i][3] = 0.f;
  }

#define O_LDA(ra, t)                                                       \
  { int tc = (t) > 8 ? 8 : (t);                                            \
    _Pragma("unroll")                                                      \
    for (int p = 0; p < 2; p++) {                                          \
      const unsigned short* sp = (tc == 0)                                 \
          ? (hb + (size_t)rgr[p] * D2 + su4[p] * 8)                        \
          : (A2b + (size_t)rgr[p] * 512 + (tc - 1) * 64 + su4[p] * 8);     \
      ra[p] = *(const uint4*)sp; } }
#define O_LDB(B, t)                                                        \
  { int tc = (t) > 8 ? 8 : (t);                                            \
    _Pragma("unroll")                                                      \
    for (int kk = 0; kk < 2; kk++) {                                       \
      int c = tc * 2 + kk;                                                 \
      B[2 * kk]     = Bq[(c * 2) * 64 + lane];                             \
      B[2 * kk + 1] = Bq[(c * 2 + 1) * 64 + lane]; } }
#define O_STA(buf, ra)                                                     \
  { _Pragma("unroll")                                                      \
    for (int p = 0; p < 2; p++) *(uint4*)&Os[buf][sph[p]] = ra[p]; }
#define O_CMP(buf, B)                                                      \
  { _Pragma("unroll")                                                      \
    for (int kk = 0; kk < 2; kk++) {                                       \
      uint4 af = *(const uint4*)&Os[buf][(wv * 16 + lrow) * 64 +           \
                                         (((kk * 4 + quad) ^ lrow) & 7) * 8]; \
      acc[0] = bmm(af, B[2 * kk], acc[0]);                                 \
      acc[1] = bmm(af, B[2 * kk + 1], acc[1]); } }

  O_LDA(rAe, 0); O_LDB(B0, 0);
  O_LDA(rAo, 1);
  O_STA(0, rAe);
  O_LDB(B1, 1);
  O_LDA(rAe, 2);
  __syncthreads();

  for (int t = 0; t < 8; t += 2) {
    O_STA(1, rAo);
    O_LDA(rAo, t + 3);
    O_CMP(0, B0);
    O_LDB(B0, t + 2);
    __syncthreads();
    O_STA(0, rAe);
    O_LDA(rAe, t + 4);
    O_CMP(1, B1);
    O_LDB(B1, t + 3);
    __syncthreads();
  }
  O_CMP(0, B0);                                   // tile 8
#undef O_LDA
#undef O_LDB
#undef O_STA
#undef O_CMP

#pragma unroll
  for (int ntl = 0; ntl < 2; ntl++) {
    int col = ntl * 16 + lrow;
    if (col < D3) {
      float bv = bias2[col];
#pragma unroll
      for (int j = 0; j < 4; j++) {
        int r = m0 + wv * 16 + quad * 4 + j;
        if (r < NN)
          out[(size_t)r * D3 + col] = acc[ntl][j] + bv;
      }
    }
  }
}

// ---------------------------------------------------------------------------
extern "C" void kernel_launch(void* const* d_in, const int* in_sizes, int n_in,
                              void* d_out, int out_size, void* d_ws,
                              size_t ws_size, hipStream_t stream) {
  const float* x_drug = (const float*)d_in[0];
  const float* drug_w = (const float*)d_in[1];
  const int*   ei     = (const int*)d_in[2];
  const float* basis1 = (const float*)d_in[3];
  const float* comp1  = (const float*)d_in[4];
  const float* root1  = (const float*)d_in[5];
  const float* bias1  = (const float*)d_in[6];
  const float* basis2 = (const float*)d_in[7];
  const float* comp2  = (const float*)d_in[8];
  const float* root2  = (const float*)d_in[9];
  const float* bias2  = (const float*)d_in[10];
  float* out = (float*)d_out;

  float* ws = (float*)d_ws;
  int*   deg  = (int*)ws;                          // 1,000,000
  int*   cnt  = deg + 1000000;                     // 10,016
  int*   off  = cnt + 10016;                       // 10,016
  int*   cur  = off + 10016;                       // 10,016
  int*   rec  = cur + 10016;                       // 500,000
  float* esc  = (float*)(rec + 500000);            // 500,000
  unsigned short* xb   = (unsigned short*)(esc + 500000);          // 640,000 f
  unsigned short* hb   = (unsigned short*)((float*)xb + 640000);   // 320,000 f
  unsigned short* Bfw  = (unsigned short*)((float*)hb + 320000);   // 131,072 f
  unsigned short* Wf1  = (unsigned short*)((float*)Bfw + 131072);  // 36,864 f
  unsigned short* Wf2  = (unsigned short*)((float*)Wf1 + 36864);   // 9,216 f
  float* R1 = (float*)Wf2 + 9216;                  // aggregation buffers
  unsigned short* A1b = (unsigned short*)R1;       // 10,000 x 1024 bf16
  unsigned short* A2b = (unsigned short*)R1;       // aliases A1b (after hlayer)

  hipMemsetAsync(deg, 0, (size_t)1000000 * 4, stream);

  // CSR build + weight prep (fused first pass)
  prep_kernel<<<(NE + W0_SZ + W1_SZ + W2_SZ + 255) / 256, 256, 0, stream>>>(
      ei, deg, drug_w, Bfw, root1, basis1, Wf1, root2, basis2, Wf2);
  cnt_kernel<<<(NN + 255) / 256, 256, 0, stream>>>(deg, cnt);
  scan_kernel<<<1, 1024, 0, stream>>>(cnt, off, cur);
  scatter_kernel<<<(NE + 255) / 256, 256, 0, stream>>>(ei, deg, cur, rec, esc);

  // x = x_drug @ drug_w
  gemm0_v5<<<(NN + 31) / 32, 256, 0, stream>>>(x_drug, Bfw, xb);

  // layer 1
  agg1e_kernel<<<(NN + 3) / 4, 256, 0, stream>>>(xb, off, rec, esc, comp1, A1b);
  hlayer_v4<<<(NN + 31) / 32, 256, 0, stream>>>(xb, A1b, Wf1, bias1, hb);

  // layer 2
  agg2e_kernel<<<(NN + 3) / 4, 256, 0, stream>>>(hb, off, rec, esc, comp2, A2b);
  out_v4<<<(NN + 31) / 32, 128, 0, stream>>>(hb, A2b, Wf2, bias2, out);
}

// Round 5
// 304.927 us; speedup vs baseline: 1.2607x; 1.2607x over previous
//
#include <hip/hip_runtime.h>

#define NN 10000    // nodes
#define RR 100      // relations
#define EE 5000     // edges per relation
#define D0 2048
#define D1 128
#define D2 64
#define D3 20
#define NE (RR*EE)  // 500000 edges total

using short8  = __attribute__((ext_vector_type(8))) short;
using float4e = __attribute__((ext_vector_type(4))) float;

__device__ __forceinline__ unsigned short f2bf(float f) {
  unsigned int u = __float_as_uint(f);
  unsigned int r = u + 0x7fffu + ((u >> 16) & 1u);   // RNE
  return (unsigned short)(r >> 16);
}
__device__ __forceinline__ float bf2f(unsigned short u) {
  return __uint_as_float(((unsigned int)u) << 16);
}
__device__ __forceinline__ unsigned int pk2(float lo, float hi) {
  return ((unsigned int)f2bf(hi) << 16) | (unsigned int)f2bf(lo);
}

// bf16x8 MFMA on uint4-typed fragments
__device__ __forceinline__ float4e bmm(uint4 a, uint4 b, float4e c) {
  return __builtin_amdgcn_mfma_f32_16x16x32_bf16(
      __builtin_bit_cast(short8, a), __builtin_bit_cast(short8, b), c, 0, 0, 0);
}

// ---------------------------------------------------------------------------
// fused prep: deg histogram + all three weight->bf16 fragment-layout packs
// frag element (for a 16-col tile nt): k = c*32 + (lane>>4)*8 + j,
//                                      n = nt*16 + (lane&15)
// ---------------------------------------------------------------------------
#define W0_SZ 262144   // drug_w frags: c 0..63, nt 0..7
#define W1_SZ 73728    // Wc1 frags:    c 0..35, nt 0..3
#define W2_SZ 18432    // Wc2 frags:    c 0..17, nt 0..1
__global__ void prep_kernel(const int* __restrict__ ei, int* __restrict__ deg,
                            const float* __restrict__ drug_w,
                            unsigned short* __restrict__ Bfw,
                            const float* __restrict__ root1,
                            const float* __restrict__ basis1,
                            unsigned short* __restrict__ Wf1,
                            const float* __restrict__ root2,
                            const float* __restrict__ basis2,
                            unsigned short* __restrict__ Wf2) {
  int gid = blockIdx.x * 256 + threadIdx.x;
  if (gid < NE) {
    int r = gid / EE, e = gid - r * EE;
    int d = ei[r * 2 * EE + EE + e];
    atomicAdd(&deg[r * NN + d], 1);
    return;
  }
  gid -= NE;
  if (gid < W0_SZ) {
    int j = gid & 7, lane = (gid >> 3) & 63, rest = gid >> 9;
    int nt = rest & 7, c = rest >> 3;
    int k = c * 32 + (lane >> 4) * 8 + j;
    int n = nt * 16 + (lane & 15);
    Bfw[gid] = f2bf(drug_w[(size_t)k * 128 + n]);
    return;
  }
  gid -= W0_SZ;
  if (gid < W1_SZ) {
    int j = gid & 7, lane = (gid >> 3) & 63, rest = gid >> 9;
    int nt = rest & 3, c = rest >> 2;
    int k = c * 32 + (lane >> 4) * 8 + j;
    int o = nt * 16 + (lane & 15);
    float v = (k < 128) ? root1[k * 64 + o] : basis1[(k - 128) * 64 + o];
    Wf1[gid] = f2bf(v);
    return;
  }
  gid -= W1_SZ;
  if (gid < W2_SZ) {
    int j = gid & 7, lane = (gid >> 3) & 63, rest = gid >> 9;
    int nt = rest & 1, c = rest >> 1;
    int k = c * 32 + (lane >> 4) * 8 + j;
    int cc = nt * 16 + (lane & 15);
    float v = 0.f;
    if (cc < 20) v = (k < 64) ? root2[k * 20 + cc] : basis2[(k - 64) * 20 + cc];
    Wf2[gid] = f2bf(v);
  }
}

__global__ void cnt_kernel(const int* __restrict__ deg, int* __restrict__ cnt) {
  int n = blockIdx.x * 256 + threadIdx.x;
  if (n >= NN) return;
  int s = 0;
  for (int r = 0; r < RR; r++) s += deg[r * NN + n];
  cnt[n] = s;
}

// ---------------------------------------------------------------------------
// single-pass scan: thread t serially scans nodes [t*10, t*10+10); one
// block-scan of the 1024 thread totals; one barrier phase.
// ---------------------------------------------------------------------------
__global__ __launch_bounds__(1024) void scan_kernel(const int* __restrict__ cnt,
                                                    int* __restrict__ off,
                                                    int* __restrict__ cur) {
  __shared__ int wsum[16];
  const int tid = threadIdx.x;
  const int wv = tid >> 6, lane = tid & 63;
  const bool act = tid < 1000;
  int loc[10];
  int s = 0;
  if (act) {
#pragma unroll
    for (int i = 0; i < 10; i++) { loc[i] = cnt[tid * 10 + i]; s += loc[i]; }
  }
  int ws = s;
#pragma unroll
  for (int d = 1; d < 64; d <<= 1) {
    int t = __shfl_up(ws, d, 64);
    if (lane >= d) ws += t;
  }
  if (lane == 63) wsum[wv] = ws;
  __syncthreads();
  if (wv == 0) {
    int w = (lane < 16) ? wsum[lane] : 0;
#pragma unroll
    for (int d = 1; d < 16; d <<= 1) {
      int t = __shfl_up(w, d, 64);
      if (lane >= d) w += t;
    }
    if (lane < 16) wsum[lane] = w;
  }
  __syncthreads();
  int excl = (wv ? wsum[wv - 1] : 0) + ws - s;
  if (act) {
    int run = excl;
#pragma unroll
    for (int i = 0; i < 10; i++) {
      off[tid * 10 + i] = run;
      cur[tid * 10 + i] = run;
      run += loc[i];
    }
  }
  if (tid == 1023) off[NN] = excl;   // s==0 for tid>=1000 -> excl == total
}

// rec = (r<<14)|src, esc = 1/max(deg,1)
__global__ void scatter_kernel(const int* __restrict__ ei,
                               const int* __restrict__ deg,
                               int* __restrict__ cur, int* __restrict__ rec,
                               float* __restrict__ esc) {
  int gid = blockIdx.x * 256 + threadIdx.x;
  if (gid >= NE) return;
  int r = gid / EE, e = gid - r * EE;
  int s = ei[r * 2 * EE + e];
  int d = ei[r * 2 * EE + EE + e];
  int p = atomicAdd(&cur[d], 1);
  rec[p] = (r << 14) | s;
  esc[p] = 1.0f / fmaxf((float)deg[r * NN + d], 1.0f);
}

// ---------------------------------------------------------------------------
// gemm0_v5: xb = bf16(x_drug @ drug_w)
// M=32 per block (313 blocks -> full CU coverage), N=128, 4 waves.
// A: coalesced fp32 loads -> bf16 -> XOR-swizzled LDS [2][32][128].
// B: direct frag-layout loads (L2-resident). 16 K-tiles of 128.
// ---------------------------------------------------------------------------
__global__ __launch_bounds__(256) void gemm0_v5(
    const float* __restrict__ A, const unsigned short* __restrict__ Bfw,
    unsigned short* __restrict__ xb) {
  __shared__ unsigned short As[2][32 * 128];
  const int tid = threadIdx.x;
  const int nw = tid >> 6, lane = tid & 63;
  const int lrow = lane & 15, quad = lane >> 4;
  const int m0 = blockIdx.x * 32;

  const int rb = tid >> 5, li = tid & 31;
  int rg[4], wo[4];
#pragma unroll
  for (int j = 0; j < 4; j++) {
    int r = rb + 8 * j;
    int g = m0 + r;
    rg[j] = g < NN ? g : NN - 1;
    wo[j] = r * 128 + (((li >> 1) ^ (r & 15)) & 15) * 8 + (li & 1) * 4;
  }

  const uint4* Bq = (const uint4*)Bfw;
  float4 rAe[4], rAo[4];
  uint4 B0[8], B1[8];
  float4e acc[2][2];
#pragma unroll
  for (int mt = 0; mt < 2; mt++)
#pragma unroll
    for (int i = 0; i < 2; i++) {
      acc[mt][i][0] = 0.f; acc[mt][i][1] = 0.f;
      acc[mt][i][2] = 0.f; acc[mt][i][3] = 0.f;
    }

#define LDA(ra, t)                                                   \
  { int tc = (t) > 15 ? 15 : (t);                                    \
    _Pragma("unroll")                                                \
    for (int j = 0; j < 4; j++)                                      \
      ra[j] = *(const float4*)(A + (size_t)rg[j] * D0 + tc * 128 + li * 4); }
#define LDB(B, t)                                                    \
  { int tc = (t) > 15 ? 15 : (t);                                    \
    _Pragma("unroll")                                                \
    for (int kk = 0; kk < 4; kk++) {                                 \
      B[2 * kk]     = Bq[((tc * 4 + kk) * 8 + 2 * nw) * 64 + lane];  \
      B[2 * kk + 1] = Bq[((tc * 4 + kk) * 8 + 2 * nw + 1) * 64 + lane]; } }
#define STA(buf, ra)                                                 \
  { _Pragma("unroll")                                                \
    for (int j = 0; j < 4; j++) {                                    \
      uint2 u; u.x = pk2(ra[j].x, ra[j].y); u.y = pk2(ra[j].z, ra[j].w); \
      *(uint2*)&As[buf][wo[j]] = u; } }
#define CMP(buf, B)                                                  \
  { _Pragma("unroll")                                                \
    for (int kk = 0; kk < 4; kk++) {                                 \
      _Pragma("unroll")                                              \
      for (int mt = 0; mt < 2; mt++) {                               \
        uint4 af = *(const uint4*)&As[buf][(mt * 16 + lrow) * 128 +  \
                                           (((kk * 4 + quad) ^ lrow) & 15) * 8]; \
        acc[mt][0] = bmm(af, B[2 * kk], acc[mt][0]);                 \
        acc[mt][1] = bmm(af, B[2 * kk + 1], acc[mt][1]); } } }

  LDA(rAe, 0); LDB(B0, 0);
  LDA(rAo, 1);
  STA(0, rAe);
  LDB(B1, 1);
  LDA(rAe, 2);
  __syncthreads();

  for (int t = 0; t < 16; t += 2) {
    STA(1, rAo);
    LDA(rAo, t + 3);
    CMP(0, B0);
    LDB(B0, t + 2);
    __syncthreads();
    STA(0, rAe);
    LDA(rAe, t + 4);
    CMP(1, B1);
    LDB(B1, t + 3);
    __syncthreads();
  }
#undef LDA
#undef LDB
#undef STA
#undef CMP

  const int c0 = nw * 32 + lrow;
#pragma unroll
  for (int mt = 0; mt < 2; mt++) {
#pragma unroll
    for (int j = 0; j < 4; j++) {
      int r = m0 + mt * 16 + quad * 4 + j;
      if (r < NN) {
        xb[(size_t)r * D1 + c0]      = f2bf(acc[mt][0][j]);
        xb[(size_t)r * D1 + c0 + 16] = f2bf(acc[mt][1][j]);
      }
    }
  }
}

// ---------------------------------------------------------------------------
// agg1e: A1b[n, b*128+i] = bf16( sum_{e->n} esc_e*comp1[r_e,b]*x[src_e,i] )
// one wave per node; lane holds 2 of 128 channels; 4-edge unroll
// (4 outstanding loads); acc[8][2]=16 regs (no spill); sc*x factored.
// ---------------------------------------------------------------------------
__global__ __launch_bounds__(256) void agg1e_kernel(
    const unsigned short* __restrict__ xb, const int* __restrict__ off,
    const int* __restrict__ rec, const float* __restrict__ esc,
    const float* __restrict__ comp, unsigned short* __restrict__ A1b) {
  __shared__ float s_comp[RR * 8];
  const int tid = threadIdx.x;
  for (int i = tid; i < RR * 8; i += 256) s_comp[i] = comp[i];
  __syncthreads();
  const int wv = tid >> 6, lane = tid & 63;
  const int n = blockIdx.x * 4 + wv;
  if (n >= NN) return;
  float acc[8][2];
#pragma unroll
  for (int b = 0; b < 8; b++) { acc[b][0] = 0.f; acc[b][1] = 0.f; }
  const int beg = off[n], end = off[n + 1];
  int idx = beg;
  for (; idx + 3 < end; idx += 4) {
    int rc[4]; float sc[4]; unsigned int xv[4];
#pragma unroll
    for (int u = 0; u < 4; u++) {
      rc[u] = rec[idx + u];
      sc[u] = esc[idx + u];
    }
#pragma unroll
    for (int u = 0; u < 4; u++)
      xv[u] = *(const unsigned int*)&xb[(size_t)(rc[u] & 16383) * D1 + lane * 2];
#pragma unroll
    for (int u = 0; u < 4; u++) {
      const float* cb = &s_comp[(rc[u] >> 14) * 8];
      float sx0 = sc[u] * __uint_as_float((xv[u] & 0xffffu) << 16);
      float sx1 = sc[u] * __uint_as_float(xv[u] & 0xffff0000u);
#pragma unroll
      for (int b = 0; b < 8; b++) {
        acc[b][0] += cb[b] * sx0;
        acc[b][1] += cb[b] * sx1;
      }
    }
  }
  for (; idx < end; idx++) {
    int rc = rec[idx];
    float sc = esc[idx];
    unsigned int xv = *(const unsigned int*)&xb[(size_t)(rc & 16383) * D1 + lane * 2];
    const float* cb = &s_comp[(rc >> 14) * 8];
    float sx0 = sc * __uint_as_float((xv & 0xffffu) << 16);
    float sx1 = sc * __uint_as_float(xv & 0xffff0000u);
#pragma unroll
    for (int b = 0; b < 8; b++) {
      acc[b][0] += cb[b] * sx0;
      acc[b][1] += cb[b] * sx1;
    }
  }
#pragma unroll
  for (int b = 0; b < 8; b++) {
    ushort2 o; o.x = f2bf(acc[b][0]); o.y = f2bf(acc[b][1]);
    *(ushort2*)&A1b[(size_t)n * 1024 + b * 128 + lane * 2] = o;
  }
}

// ---------------------------------------------------------------------------
// agg2e: one wave per node; lane holds 1 of 64 channels; 4-edge unroll;
// acc[8]=8 regs; sc*h factored.
// ---------------------------------------------------------------------------
__global__ __launch_bounds__(256) void agg2e_kernel(
    const unsigned short* __restrict__ hb, const int* __restrict__ off,
    const int* __restrict__ rec, const float* __restrict__ esc,
    const float* __restrict__ comp, unsigned short* __restrict__ A2b) {
  __shared__ float s_comp[RR * 8];
  const int tid = threadIdx.x;
  for (int i = tid; i < RR * 8; i += 256) s_comp[i] = comp[i];
  __syncthreads();
  const int wv = tid >> 6, lane = tid & 63;
  const int n = blockIdx.x * 4 + wv;
  if (n >= NN) return;
  float acc[8];
#pragma unroll
  for (int b = 0; b < 8; b++) acc[b] = 0.f;
  const int beg = off[n], end = off[n + 1];
  int idx = beg;
  for (; idx + 3 < end; idx += 4) {
    int rc[4]; float sc[4]; float hv[4];
#pragma unroll
    for (int u = 0; u < 4; u++) {
      rc[u] = rec[idx + u];
      sc[u] = esc[idx + u];
    }
#pragma unroll
    for (int u = 0; u < 4; u++)
      hv[u] = bf2f(hb[(size_t)(rc[u] & 16383) * D2 + lane]);
#pragma unroll
    for (int u = 0; u < 4; u++) {
      const float* cb = &s_comp[(rc[u] >> 14) * 8];
      float sh = sc[u] * hv[u];
#pragma unroll
      for (int b = 0; b < 8; b++) acc[b] += cb[b] * sh;
    }
  }
  for (; idx < end; idx++) {
    int rc = rec[idx];
    float sc = esc[idx];
    float hv = bf2f(hb[(size_t)(rc & 16383) * D2 + lane]);
    const float* cb = &s_comp[(rc >> 14) * 8];
    float sh = sc * hv;
#pragma unroll
    for (int b = 0; b < 8; b++) acc[b] += cb[b] * sh;
  }
#pragma unroll
  for (int b = 0; b < 8; b++)
    A2b[(size_t)n * 512 + b * 64 + lane] = f2bf(acc[b]);
}

// ---------------------------------------------------------------------------
// hlayer_v4: hb = bf16(relu([xb|A1b](K=1152) @ Wc1 + bias1))
// M=32 (313 blocks), N=64, 4 waves. A staged coalesced bf16 -> swizzled LDS;
// 9 K-tiles of 128. B direct frag-layout.
// ---------------------------------------------------------------------------
__global__ __launch_bounds__(256) void hlayer_v4(
    const unsigned short* __restrict__ xb, const unsigned short* __restrict__ A1b,
    const unsigned short* __restrict__ Wf, const float* __restrict__ bias1,
    unsigned short* __restrict__ hb) {
  __shared__ unsigned short Hs[2][32 * 128];
  const int tid = threadIdx.x;
  const int wv = tid >> 6, lane = tid & 63;
  const int lrow = lane & 15, quad = lane >> 4;
  const int m0 = blockIdx.x * 32;
  const int mt = wv >> 1, nb = (wv & 1) * 2;

  int rgr[2], su4[2], sph[2];
#pragma unroll
  for (int p = 0; p < 2; p++) {
    int idx = tid + p * 256;
    int r = idx >> 4, u = idx & 15;
    int g = m0 + r;
    rgr[p] = g < NN ? g : NN - 1;
    su4[p] = u;
    sph[p] = r * 128 + ((u ^ (r & 15)) & 15) * 8;
  }

  const uint4* Bq = (const uint4*)Wf;
  uint4 rAe[2], rAo[2];
  uint4 B0[8], B1[8];
  float4e acc[2];
#pragma unroll
  for (int i = 0; i < 2; i++) {
    acc[i][0] = 0.f; acc[i][1] = 0.f; acc[i][2] = 0.f; acc[i][3] = 0.f;
  }

#define H_LDA(ra, t)                                                       \
  { int tc = (t) > 8 ? 8 : (t);                                            \
    _Pragma("unroll")                                                      \
    for (int p = 0; p < 2; p++) {                                          \
      const unsigned short* sp = (tc == 0)                                 \
          ? (xb + (size_t)rgr[p] * D1 + su4[p] * 8)                        \
          : (A1b + (size_t)rgr[p] * 1024 + (tc - 1) * 128 + su4[p] * 8);   \
      ra[p] = *(const uint4*)sp; } }
#define H_LDB(B, t)                                                        \
  { int tc = (t) > 8 ? 8 : (t);                                            \
    _Pragma("unroll")                                                      \
    for (int kk = 0; kk < 4; kk++) {                                       \
      int c = tc * 4 + kk;                                                 \
      B[2 * kk]     = Bq[(c * 4 + nb) * 64 + lane];                        \
      B[2 * kk + 1] = Bq[(c * 4 + nb + 1) * 64 + lane]; } }
#define H_STA(buf, ra)                                                     \
  { _Pragma("unroll")                                                      \
    for (int p = 0; p < 2; p++) *(uint4*)&Hs[buf][sph[p]] = ra[p]; }
#define H_CMP(buf, B)                                                      \
  { _Pragma("unroll")                                                      \
    for (int kk = 0; kk < 4; kk++) {                                       \
      uint4 af = *(const uint4*)&Hs[buf][(mt * 16 + lrow) * 128 +          \
                                         (((kk * 4 + quad) ^ lrow) & 15) * 8]; \
      acc[0] = bmm(af, B[2 * kk], acc[0]);                                 \
      acc[1] = bmm(af, B[2 * kk + 1], acc[1]); } }

  H_LDA(rAe, 0); H_LDB(B0, 0);
  H_LDA(rAo, 1);
  H_STA(0, rAe);
  H_LDB(B1, 1);
  H_LDA(rAe, 2);
  __syncthreads();

  for (int t = 0; t < 8; t += 2) {
    H_STA(1, rAo);
    H_LDA(rAo, t + 3);
    H_CMP(0, B0);
    H_LDB(B0, t + 2);
    __syncthreads();
    H_STA(0, rAe);
    H_LDA(rAe, t + 4);
    H_CMP(1, B1);
    H_LDB(B1, t + 3);
    __syncthreads();
  }
  H_CMP(0, B0);                                   // tile 8
#undef H_LDA
#undef H_LDB
#undef H_STA
#undef H_CMP

#pragma unroll
  for (int ntl = 0; ntl < 2; ntl++) {
    int col = (nb + ntl) * 16 + lrow;
    float bv = bias1[col];
#pragma unroll
    for (int j = 0; j < 4; j++) {
      int r = m0 + mt * 16 + quad * 4 + j;
      if (r < NN)
        hb[(size_t)r * D2 + col] = f2bf(fmaxf(acc[ntl][j] + bv, 0.f));
    }
  }
}

// ---------------------------------------------------------------------------
// out_v4: out = [hb|A2b](K=576) @ Wc2 + bias2
// ---------------------------------------------------------------------------
__global__ __launch_bounds__(128) void out_v4(
    const unsigned short* __restrict__ hb, const unsigned short* __restrict__ A2b,
    const unsigned short* __restrict__ Wf, const float* __restrict__ bias2,
    float* __restrict__ out) {
  __shared__ unsigned short Os[2][32 * 64];
  const int tid = threadIdx.x;
  const int wv = tid >> 6, lane = tid & 63;
  const int lrow = lane & 15, quad = lane >> 4;
  const int m0 = blockIdx.x * 32;

  int rgr[2], su4[2], sph[2];
#pragma unroll
  for (int p = 0; p < 2; p++) {
    int idx = tid + p * 128;
    int r = idx >> 3, u = idx & 7;
    int g = m0 + r;
    rgr[p] = g < NN ? g : NN - 1;
    su4[p] = u;
    sph[p] = r * 64 + ((u ^ (r & 7)) & 7) * 8;
  }

  const uint4* Bq = (const uint4*)Wf;
  uint4 rAe[2], rAo[2];
  uint4 B0[4], B1[4];
  float4e acc[2];
#pragma unroll
  for (int i = 0; i < 2; i++) {
    acc[i][0] = 0.f; acc[i][1] = 0.f; acc[i][2] = 0.f; acc[i][3] = 0.f;
  }

#define O_LDA(ra, t)                                                       \
  { int tc = (t) > 8 ? 8 : (t);                                            \
    _Pragma("unroll")                                                      \
    for (int p = 0; p < 2; p++) {                                          \
      const unsigned short* sp = (tc == 0)                                 \
          ? (hb + (size_t)rgr[p] * D2 + su4[p] * 8)                        \
          : (A2b + (size_t)rgr[p] * 512 + (tc - 1) * 64 + su4[p] * 8);     \
      ra[p] = *(const uint4*)sp; } }
#define O_LDB(B, t)                                                        \
  { int tc = (t) > 8 ? 8 : (t);                                            \
    _Pragma("unroll")                                                      \
    for (int kk = 0; kk < 2; kk++) {                                       \
      int c = tc * 2 + kk;                                                 \
      B[2 * kk]     = Bq[(c * 2) * 64 + lane];                             \
      B[2 * kk + 1] = Bq[(c * 2 + 1) * 64 + lane]; } }
#define O_STA(buf, ra)                                                     \
  { _Pragma("unroll")                                                      \
    for (int p = 0; p < 2; p++) *(uint4*)&Os[buf][sph[p]] = ra[p]; }
#define O_CMP(buf, B)                                                      \
  { _Pragma("unroll")                                                      \
    for (int kk = 0; kk < 2; kk++) {                                       \
      uint4 af = *(const uint4*)&Os[buf][(wv * 16 + lrow) * 64 +           \
                                         (((kk * 4 + quad) ^ lrow) & 7) * 8]; \
      acc[0] = bmm(af, B[2 * kk], acc[0]);                                 \
      acc[1] = bmm(af, B[2 * kk + 1], acc[1]); } }

  O_LDA(rAe, 0); O_LDB(B0, 0);
  O_LDA(rAo, 1);
  O_STA(0, rAe);
  O_LDB(B1, 1);
  O_LDA(rAe, 2);
  __syncthreads();

  for (int t = 0; t < 8; t += 2) {
    O_STA(1, rAo);
    O_LDA(rAo, t + 3);
    O_CMP(0, B0);
    O_LDB(B0, t + 2);
    __syncthreads();
    O_STA(0, rAe);
    O_LDA(rAe, t + 4);
    O_CMP(1, B1);
    O_LDB(B1, t + 3);
    __syncthreads();
  }
  O_CMP(0, B0);                                   // tile 8
#undef O_LDA
#undef O_LDB
#undef O_STA
#undef O_CMP

#pragma unroll
  for (int ntl = 0; ntl < 2; ntl++) {
    int col = ntl * 16 + lrow;
    if (col < D3) {
      float bv = bias2[col];
#pragma unroll
      for (int j = 0; j < 4; j++) {
        int r = m0 + wv * 16 + quad * 4 + j;
        if (r < NN)
          out[(size_t)r * D3 + col] = acc[ntl][j] + bv;
      }
    }
  }
}

// ---------------------------------------------------------------------------
extern "C" void kernel_launch(void* const* d_in, const int* in_sizes, int n_in,
                              void* d_out, int out_size, void* d_ws,
                              size_t ws_size, hipStream_t stream) {
  const float* x_drug = (const float*)d_in[0];
  const float* drug_w = (const float*)d_in[1];
  const int*   ei     = (const int*)d_in[2];
  const float* basis1 = (const float*)d_in[3];
  const float* comp1  = (const float*)d_in[4];
  const float* root1  = (const float*)d_in[5];
  const float* bias1  = (const float*)d_in[6];
  const float* basis2 = (const float*)d_in[7];
  const float* comp2  = (const float*)d_in[8];
  const float* root2  = (const float*)d_in[9];
  const float* bias2  = (const float*)d_in[10];
  float* out = (float*)d_out;

  float* ws = (float*)d_ws;
  int*   deg  = (int*)ws;                          // 1,000,000
  int*   cnt  = deg + 1000000;                     // 10,016
  int*   off  = cnt + 10016;                       // 10,016
  int*   cur  = off + 10016;                       // 10,016
  int*   rec  = cur + 10016;                       // 500,000
  float* esc  = (float*)(rec + 500000);            // 500,000
  unsigned short* xb   = (unsigned short*)(esc + 500000);          // 640,000 f
  unsigned short* hb   = (unsigned short*)((float*)xb + 640000);   // 320,000 f
  unsigned short* Bfw  = (unsigned short*)((float*)hb + 320000);   // 131,072 f
  unsigned short* Wf1  = (unsigned short*)((float*)Bfw + 131072);  // 36,864 f
  unsigned short* Wf2  = (unsigned short*)((float*)Wf1 + 36864);   // 9,216 f
  float* R1 = (float*)Wf2 + 9216;                  // aggregation buffers
  unsigned short* A1b = (unsigned short*)R1;       // 10,000 x 1024 bf16
  unsigned short* A2b = (unsigned short*)R1;       // aliases A1b (after hlayer)

  hipMemsetAsync(deg, 0, (size_t)1000000 * 4, stream);

  // CSR build + weight prep (fused first pass)
  prep_kernel<<<(NE + W0_SZ + W1_SZ + W2_SZ + 255) / 256, 256, 0, stream>>>(
      ei, deg, drug_w, Bfw, root1, basis1, Wf1, root2, basis2, Wf2);
  cnt_kernel<<<(NN + 255) / 256, 256, 0, stream>>>(deg, cnt);
  scan_kernel<<<1, 1024, 0, stream>>>(cnt, off, cur);
  scatter_kernel<<<(NE + 255) / 256, 256, 0, stream>>>(ei, deg, cur, rec, esc);

  // x = x_drug @ drug_w
  gemm0_v5<<<(NN + 31) / 32, 256, 0, stream>>>(x_drug, Bfw, xb);

  // layer 1
  agg1e_kernel<<<(NN + 3) / 4, 256, 0, stream>>>(xb, off, rec, esc, comp1, A1b);
  hlayer_v4<<<(NN + 31) / 32, 256, 0, stream>>>(xb, A1b, Wf1, bias1, hb);

  // layer 2
  agg2e_kernel<<<(NN + 3) / 4, 256, 0, stream>>>(hb, off, rec, esc, comp2, A2b);
  out_v4<<<(NN + 31) / 32, 128, 0, stream>>>(hb, A2b, Wf2, bias2, out);
}

// Round 6
// 302.436 us; speedup vs baseline: 1.2710x; 1.0082x over previous
//
#include <hip/hip_runtime.h>

#define NN 10000    // nodes
#define RR 100      // relations
#define EE 5000     // edges per relation
#define D0 2048
#define D1 128
#define D2 64
#define D3 20
#define NE (RR*EE)  // 500000 edges total

using short8  = __attribute__((ext_vector_type(8))) short;
using float4e = __attribute__((ext_vector_type(4))) float;

__device__ __forceinline__ unsigned short f2bf(float f) {
  unsigned int u = __float_as_uint(f);
  unsigned int r = u + 0x7fffu + ((u >> 16) & 1u);   // RNE
  return (unsigned short)(r >> 16);
}
__device__ __forceinline__ float bf2f(unsigned short u) {
  return __uint_as_float(((unsigned int)u) << 16);
}
__device__ __forceinline__ unsigned int pk2(float lo, float hi) {
  return ((unsigned int)f2bf(hi) << 16) | (unsigned int)f2bf(lo);
}

// bf16x8 MFMA on uint4-typed fragments
__device__ __forceinline__ float4e bmm(uint4 a, uint4 b, float4e c) {
  return __builtin_amdgcn_mfma_f32_16x16x32_bf16(
      __builtin_bit_cast(short8, a), __builtin_bit_cast(short8, b), c, 0, 0, 0);
}

// ---------------------------------------------------------------------------
// fused prep: deg histogram + all three weight->bf16 fragment-layout packs
// frag element (for a 16-col tile nt): k = c*32 + (lane>>4)*8 + j,
//                                      n = nt*16 + (lane&15)
// ---------------------------------------------------------------------------
#define W0_SZ 262144   // drug_w frags: c 0..63, nt 0..7
#define W1_SZ 73728    // Wc1 frags:    c 0..35, nt 0..3
#define W2_SZ 18432    // Wc2 frags:    c 0..17, nt 0..1
__global__ void prep_kernel(const int* __restrict__ ei, int* __restrict__ deg,
                            const float* __restrict__ drug_w,
                            unsigned short* __restrict__ Bfw,
                            const float* __restrict__ root1,
                            const float* __restrict__ basis1,
                            unsigned short* __restrict__ Wf1,
                            const float* __restrict__ root2,
                            const float* __restrict__ basis2,
                            unsigned short* __restrict__ Wf2) {
  int gid = blockIdx.x * 256 + threadIdx.x;
  if (gid < NE) {
    int r = gid / EE, e = gid - r * EE;
    int d = ei[r * 2 * EE + EE + e];
    atomicAdd(&deg[r * NN + d], 1);
    return;
  }
  gid -= NE;
  if (gid < W0_SZ) {
    int j = gid & 7, lane = (gid >> 3) & 63, rest = gid >> 9;
    int nt = rest & 7, c = rest >> 3;
    int k = c * 32 + (lane >> 4) * 8 + j;
    int n = nt * 16 + (lane & 15);
    Bfw[gid] = f2bf(drug_w[(size_t)k * 128 + n]);
    return;
  }
  gid -= W0_SZ;
  if (gid < W1_SZ) {
    int j = gid & 7, lane = (gid >> 3) & 63, rest = gid >> 9;
    int nt = rest & 3, c = rest >> 2;
    int k = c * 32 + (lane >> 4) * 8 + j;
    int o = nt * 16 + (lane & 15);
    float v = (k < 128) ? root1[k * 64 + o] : basis1[(k - 128) * 64 + o];
    Wf1[gid] = f2bf(v);
    return;
  }
  gid -= W1_SZ;
  if (gid < W2_SZ) {
    int j = gid & 7, lane = (gid >> 3) & 63, rest = gid >> 9;
    int nt = rest & 1, c = rest >> 1;
    int k = c * 32 + (lane >> 4) * 8 + j;
    int cc = nt * 16 + (lane & 15);
    float v = 0.f;
    if (cc < 20) v = (k < 64) ? root2[k * 20 + cc] : basis2[(k - 64) * 20 + cc];
    Wf2[gid] = f2bf(v);
  }
}

__global__ void cnt_kernel(const int* __restrict__ deg, int* __restrict__ cnt) {
  int n = blockIdx.x * 256 + threadIdx.x;
  if (n >= NN) return;
  int s = 0;
  for (int r = 0; r < RR; r++) s += deg[r * NN + n];
  cnt[n] = s;
}

// ---------------------------------------------------------------------------
// single-pass scan: thread t serially scans nodes [t*10, t*10+10); one
// block-scan of the 1024 thread totals; one barrier phase.
// ---------------------------------------------------------------------------
__global__ __launch_bounds__(1024) void scan_kernel(const int* __restrict__ cnt,
                                                    int* __restrict__ off,
                                                    int* __restrict__ cur) {
  __shared__ int wsum[16];
  const int tid = threadIdx.x;
  const int wv = tid >> 6, lane = tid & 63;
  const bool act = tid < 1000;
  int loc[10];
  int s = 0;
  if (act) {
#pragma unroll
    for (int i = 0; i < 10; i++) { loc[i] = cnt[tid * 10 + i]; s += loc[i]; }
  }
  int ws = s;
#pragma unroll
  for (int d = 1; d < 64; d <<= 1) {
    int t = __shfl_up(ws, d, 64);
    if (lane >= d) ws += t;
  }
  if (lane == 63) wsum[wv] = ws;
  __syncthreads();
  if (wv == 0) {
    int w = (lane < 16) ? wsum[lane] : 0;
#pragma unroll
    for (int d = 1; d < 16; d <<= 1) {
      int t = __shfl_up(w, d, 64);
      if (lane >= d) w += t;
    }
    if (lane < 16) wsum[lane] = w;
  }
  __syncthreads();
  int excl = (wv ? wsum[wv - 1] : 0) + ws - s;
  if (act) {
    int run = excl;
#pragma unroll
    for (int i = 0; i < 10; i++) {
      off[tid * 10 + i] = run;
      cur[tid * 10 + i] = run;
      run += loc[i];
    }
  }
  if (tid == 1023) off[NN] = excl;   // s==0 for tid>=1000 -> excl == total
}

// rec = (r<<14)|src, esc = 1/max(deg,1)
__global__ void scatter_kernel(const int* __restrict__ ei,
                               const int* __restrict__ deg,
                               int* __restrict__ cur, int* __restrict__ rec,
                               float* __restrict__ esc) {
  int gid = blockIdx.x * 256 + threadIdx.x;
  if (gid >= NE) return;
  int r = gid / EE, e = gid - r * EE;
  int s = ei[r * 2 * EE + e];
  int d = ei[r * 2 * EE + EE + e];
  int p = atomicAdd(&cur[d], 1);
  rec[p] = (r << 14) | s;
  esc[p] = 1.0f / fmaxf((float)deg[r * NN + d], 1.0f);
}

// ---------------------------------------------------------------------------
// gemm0_v5: xb = bf16(x_drug @ drug_w)
// M=32 per block (313 blocks -> full CU coverage), N=128, 4 waves.
// A: coalesced fp32 loads -> bf16 -> XOR-swizzled LDS [2][32][128].
// B: direct frag-layout loads (L2-resident). 16 K-tiles of 128.
// ---------------------------------------------------------------------------
__global__ __launch_bounds__(256) void gemm0_v5(
    const float* __restrict__ A, const unsigned short* __restrict__ Bfw,
    unsigned short* __restrict__ xb) {
  __shared__ unsigned short As[2][32 * 128];
  const int tid = threadIdx.x;
  const int nw = tid >> 6, lane = tid & 63;
  const int lrow = lane & 15, quad = lane >> 4;
  const int m0 = blockIdx.x * 32;

  const int rb = tid >> 5, li = tid & 31;
  int rg[4], wo[4];
#pragma unroll
  for (int j = 0; j < 4; j++) {
    int r = rb + 8 * j;
    int g = m0 + r;
    rg[j] = g < NN ? g : NN - 1;
    wo[j] = r * 128 + (((li >> 1) ^ (r & 15)) & 15) * 8 + (li & 1) * 4;
  }

  const uint4* Bq = (const uint4*)Bfw;
  float4 rAe[4], rAo[4];
  uint4 B0[8], B1[8];
  float4e acc[2][2];
#pragma unroll
  for (int mt = 0; mt < 2; mt++)
#pragma unroll
    for (int i = 0; i < 2; i++) {
      acc[mt][i][0] = 0.f; acc[mt][i][1] = 0.f;
      acc[mt][i][2] = 0.f; acc[mt][i][3] = 0.f;
    }

#define LDA(ra, t)                                                   \
  { int tc = (t) > 15 ? 15 : (t);                                    \
    _Pragma("unroll")                                                \
    for (int j = 0; j < 4; j++)                                      \
      ra[j] = *(const float4*)(A + (size_t)rg[j] * D0 + tc * 128 + li * 4); }
#define LDB(B, t)                                                    \
  { int tc = (t) > 15 ? 15 : (t);                                    \
    _Pragma("unroll")                                                \
    for (int kk = 0; kk < 4; kk++) {                                 \
      B[2 * kk]     = Bq[((tc * 4 + kk) * 8 + 2 * nw) * 64 + lane];  \
      B[2 * kk + 1] = Bq[((tc * 4 + kk) * 8 + 2 * nw + 1) * 64 + lane]; } }
#define STA(buf, ra)                                                 \
  { _Pragma("unroll")                                                \
    for (int j = 0; j < 4; j++) {                                    \
      uint2 u; u.x = pk2(ra[j].x, ra[j].y); u.y = pk2(ra[j].z, ra[j].w); \
      *(uint2*)&As[buf][wo[j]] = u; } }
#define CMP(buf, B)                                                  \
  { _Pragma("unroll")                                                \
    for (int kk = 0; kk < 4; kk++) {                                 \
      _Pragma("unroll")                                              \
      for (int mt = 0; mt < 2; mt++) {                               \
        uint4 af = *(const uint4*)&As[buf][(mt * 16 + lrow) * 128 +  \
                                           (((kk * 4 + quad) ^ lrow) & 15) * 8]; \
        acc[mt][0] = bmm(af, B[2 * kk], acc[mt][0]);                 \
        acc[mt][1] = bmm(af, B[2 * kk + 1], acc[mt][1]); } } }

  LDA(rAe, 0); LDB(B0, 0);
  LDA(rAo, 1);
  STA(0, rAe);
  LDB(B1, 1);
  LDA(rAe, 2);
  __syncthreads();

  for (int t = 0; t < 16; t += 2) {
    STA(1, rAo);
    LDA(rAo, t + 3);
    CMP(0, B0);
    LDB(B0, t + 2);
    __syncthreads();
    STA(0, rAe);
    LDA(rAe, t + 4);
    CMP(1, B1);
    LDB(B1, t + 3);
    __syncthreads();
  }
#undef LDA
#undef LDB
#undef STA
#undef CMP

  const int c0 = nw * 32 + lrow;
#pragma unroll
  for (int mt = 0; mt < 2; mt++) {
#pragma unroll
    for (int j = 0; j < 4; j++) {
      int r = m0 + mt * 16 + quad * 4 + j;
      if (r < NN) {
        xb[(size_t)r * D1 + c0]      = f2bf(acc[mt][0][j]);
        xb[(size_t)r * D1 + c0 + 16] = f2bf(acc[mt][1][j]);
      }
    }
  }
}

// ---------------------------------------------------------------------------
// agg1e: A1b[n, b*128+i] = bf16( sum_{e->n} esc_e*comp1[r_e,b]*x[src_e,i] )
// one wave per node; lane holds 2 of 128 channels; 8-edge unroll
// (8 outstanding gathers); acc[8][2]=16 regs (no spill); sc*x factored.
// ---------------------------------------------------------------------------
__global__ __launch_bounds__(256) void agg1e_kernel(
    const unsigned short* __restrict__ xb, const int* __restrict__ off,
    const int* __restrict__ rec, const float* __restrict__ esc,
    const float* __restrict__ comp, unsigned short* __restrict__ A1b) {
  __shared__ float s_comp[RR * 8];
  const int tid = threadIdx.x;
  for (int i = tid; i < RR * 8; i += 256) s_comp[i] = comp[i];
  __syncthreads();
  const int wv = tid >> 6, lane = tid & 63;
  const int n = blockIdx.x * 4 + wv;
  if (n >= NN) return;
  float acc[8][2];
#pragma unroll
  for (int b = 0; b < 8; b++) { acc[b][0] = 0.f; acc[b][1] = 0.f; }
  const int beg = off[n], end = off[n + 1];
  int idx = beg;
  for (; idx + 7 < end; idx += 8) {
    int rc[8]; float sc[8]; unsigned int xv[8];
#pragma unroll
    for (int u = 0; u < 8; u++) {
      rc[u] = rec[idx + u];
      sc[u] = esc[idx + u];
    }
#pragma unroll
    for (int u = 0; u < 8; u++)
      xv[u] = *(const unsigned int*)&xb[(size_t)(rc[u] & 16383) * D1 + lane * 2];
#pragma unroll
    for (int u = 0; u < 8; u++) {
      const float* cb = &s_comp[(rc[u] >> 14) * 8];
      float sx0 = sc[u] * __uint_as_float((xv[u] & 0xffffu) << 16);
      float sx1 = sc[u] * __uint_as_float(xv[u] & 0xffff0000u);
#pragma unroll
      for (int b = 0; b < 8; b++) {
        acc[b][0] += cb[b] * sx0;
        acc[b][1] += cb[b] * sx1;
      }
    }
  }
  for (; idx < end; idx++) {
    int rc = rec[idx];
    float sc = esc[idx];
    unsigned int xv = *(const unsigned int*)&xb[(size_t)(rc & 16383) * D1 + lane * 2];
    const float* cb = &s_comp[(rc >> 14) * 8];
    float sx0 = sc * __uint_as_float((xv & 0xffffu) << 16);
    float sx1 = sc * __uint_as_float(xv & 0xffff0000u);
#pragma unroll
    for (int b = 0; b < 8; b++) {
      acc[b][0] += cb[b] * sx0;
      acc[b][1] += cb[b] * sx1;
    }
  }
#pragma unroll
  for (int b = 0; b < 8; b++) {
    ushort2 o; o.x = f2bf(acc[b][0]); o.y = f2bf(acc[b][1]);
    *(ushort2*)&A1b[(size_t)n * 1024 + b * 128 + lane * 2] = o;
  }
}

// ---------------------------------------------------------------------------
// agg2e: one wave per node; lane holds 1 of 64 channels; 8-edge unroll;
// acc[8]=8 regs; sc*h factored.
// ---------------------------------------------------------------------------
__global__ __launch_bounds__(256) void agg2e_kernel(
    const unsigned short* __restrict__ hb, const int* __restrict__ off,
    const int* __restrict__ rec, const float* __restrict__ esc,
    const float* __restrict__ comp, unsigned short* __restrict__ A2b) {
  __shared__ float s_comp[RR * 8];
  const int tid = threadIdx.x;
  for (int i = tid; i < RR * 8; i += 256) s_comp[i] = comp[i];
  __syncthreads();
  const int wv = tid >> 6, lane = tid & 63;
  const int n = blockIdx.x * 4 + wv;
  if (n >= NN) return;
  float acc[8];
#pragma unroll
  for (int b = 0; b < 8; b++) acc[b] = 0.f;
  const int beg = off[n], end = off[n + 1];
  int idx = beg;
  for (; idx + 7 < end; idx += 8) {
    int rc[8]; float sc[8]; float hv[8];
#pragma unroll
    for (int u = 0; u < 8; u++) {
      rc[u] = rec[idx + u];
      sc[u] = esc[idx + u];
    }
#pragma unroll
    for (int u = 0; u < 8; u++)
      hv[u] = bf2f(hb[(size_t)(rc[u] & 16383) * D2 + lane]);
#pragma unroll
    for (int u = 0; u < 8; u++) {
      const float* cb = &s_comp[(rc[u] >> 14) * 8];
      float sh = sc[u] * hv[u];
#pragma unroll
      for (int b = 0; b < 8; b++) acc[b] += cb[b] * sh;
    }
  }
  for (; idx < end; idx++) {
    int rc = rec[idx];
    float sc = esc[idx];
    float hv = bf2f(hb[(size_t)(rc & 16383) * D2 + lane]);
    const float* cb = &s_comp[(rc >> 14) * 8];
    float sh = sc * hv;
#pragma unroll
    for (int b = 0; b < 8; b++) acc[b] += cb[b] * sh;
  }
#pragma unroll
  for (int b = 0; b < 8; b++)
    A2b[(size_t)n * 512 + b * 64 + lane] = f2bf(acc[b]);
}

// ---------------------------------------------------------------------------
// hlayer_v4: hb = bf16(relu([xb|A1b](K=1152) @ Wc1 + bias1))
// M=32 (313 blocks), N=64, 4 waves. A staged coalesced bf16 -> swizzled LDS;
// 9 K-tiles of 128. B direct frag-layout.
// ---------------------------------------------------------------------------
__global__ __launch_bounds__(256) void hlayer_v4(
    const unsigned short* __restrict__ xb, const unsigned short* __restrict__ A1b,
    const unsigned short* __restrict__ Wf, const float* __restrict__ bias1,
    unsigned short* __restrict__ hb) {
  __shared__ unsigned short Hs[2][32 * 128];
  const int tid = threadIdx.x;
  const int wv = tid >> 6, lane = tid & 63;
  const int lrow = lane & 15, quad = lane >> 4;
  const int m0 = blockIdx.x * 32;
  const int mt = wv >> 1, nb = (wv & 1) * 2;

  int rgr[2], su4[2], sph[2];
#pragma unroll
  for (int p = 0; p < 2; p++) {
    int idx = tid + p * 256;
    int r = idx >> 4, u = idx & 15;
    int g = m0 + r;
    rgr[p] = g < NN ? g : NN - 1;
    su4[p] = u;
    sph[p] = r * 128 + ((u ^ (r & 15)) & 15) * 8;
  }

  const uint4* Bq = (const uint4*)Wf;
  uint4 rAe[2], rAo[2];
  uint4 B0[8], B1[8];
  float4e acc[2];
#pragma unroll
  for (int i = 0; i < 2; i++) {
    acc[i][0] = 0.f; acc[i][1] = 0.f; acc[i][2] = 0.f; acc[i][3] = 0.f;
  }

#define H_LDA(ra, t)                                                       \
  { int tc = (t) > 8 ? 8 : (t);                                            \
    _Pragma("unroll")                                                      \
    for (int p = 0; p < 2; p++) {                                          \
      const unsigned short* sp = (tc == 0)                                 \
          ? (xb + (size_t)rgr[p] * D1 + su4[p] * 8)                        \
          : (A1b + (size_t)rgr[p] * 1024 + (tc - 1) * 128 + su4[p] * 8);   \
      ra[p] = *(const uint4*)sp; } }
#define H_LDB(B, t)                                                        \
  { int tc = (t) > 8 ? 8 : (t);                                            \
    _Pragma("unroll")                                                      \
    for (int kk = 0; kk < 4; kk++) {                                       \
      int c = tc * 4 + kk;                                                 \
      B[2 * kk]     = Bq[(c * 4 + nb) * 64 + lane];                        \
      B[2 * kk + 1] = Bq[(c * 4 + nb + 1) * 64 + lane]; } }
#define H_STA(buf, ra)                                                     \
  { _Pragma("unroll")                                                      \
    for (int p = 0; p < 2; p++) *(uint4*)&Hs[buf][sph[p]] = ra[p]; }
#define H_CMP(buf, B)                                                      \
  { _Pragma("unroll")                                                      \
    for (int kk = 0; kk < 4; kk++) {                                       \
      uint4 af = *(const uint4*)&Hs[buf][(mt * 16 + lrow) * 128 +          \
                                         (((kk * 4 + quad) ^ lrow) & 15) * 8]; \
      acc[0] = bmm(af, B[2 * kk], acc[0]);                                 \
      acc[1] = bmm(af, B[2 * kk + 1], acc[1]); } }

  H_LDA(rAe, 0); H_LDB(B0, 0);
  H_LDA(rAo, 1);
  H_STA(0, rAe);
  H_LDB(B1, 1);
  H_LDA(rAe, 2);
  __syncthreads();

  for (int t = 0; t < 8; t += 2) {
    H_STA(1, rAo);
    H_LDA(rAo, t + 3);
    H_CMP(0, B0);
    H_LDB(B0, t + 2);
    __syncthreads();
    H_STA(0, rAe);
    H_LDA(rAe, t + 4);
    H_CMP(1, B1);
    H_LDB(B1, t + 3);
    __syncthreads();
  }
  H_CMP(0, B0);                                   // tile 8
#undef H_LDA
#undef H_LDB
#undef H_STA
#undef H_CMP

#pragma unroll
  for (int ntl = 0; ntl < 2; ntl++) {
    int col = (nb + ntl) * 16 + lrow;
    float bv = bias1[col];
#pragma unroll
    for (int j = 0; j < 4; j++) {
      int r = m0 + mt * 16 + quad * 4 + j;
      if (r < NN)
        hb[(size_t)r * D2 + col] = f2bf(fmaxf(acc[ntl][j] + bv, 0.f));
    }
  }
}

// ---------------------------------------------------------------------------
// out_v4: out = [hb|A2b](K=576) @ Wc2 + bias2
// ---------------------------------------------------------------------------
__global__ __launch_bounds__(128) void out_v4(
    const unsigned short* __restrict__ hb, const unsigned short* __restrict__ A2b,
    const unsigned short* __restrict__ Wf, const float* __restrict__ bias2,
    float* __restrict__ out) {
  __shared__ unsigned short Os[2][32 * 64];
  const int tid = threadIdx.x;
  const int wv = tid >> 6, lane = tid & 63;
  const int lrow = lane & 15, quad = lane >> 4;
  const int m0 = blockIdx.x * 32;

  int rgr[2], su4[2], sph[2];
#pragma unroll
  for (int p = 0; p < 2; p++) {
    int idx = tid + p * 128;
    int r = idx >> 3, u = idx & 7;
    int g = m0 + r;
    rgr[p] = g < NN ? g : NN - 1;
    su4[p] = u;
    sph[p] = r * 64 + ((u ^ (r & 7)) & 7) * 8;
  }

  const uint4* Bq = (const uint4*)Wf;
  uint4 rAe[2], rAo[2];
  uint4 B0[4], B1[4];
  float4e acc[2];
#pragma unroll
  for (int i = 0; i < 2; i++) {
    acc[i][0] = 0.f; acc[i][1] = 0.f; acc[i][2] = 0.f; acc[i][3] = 0.f;
  }

#define O_LDA(ra, t)                                                       \
  { int tc = (t) > 8 ? 8 : (t);                                            \
    _Pragma("unroll")                                                      \
    for (int p = 0; p < 2; p++) {                                          \
      const unsigned short* sp = (tc == 0)                                 \
          ? (hb + (size_t)rgr[p] * D2 + su4[p] * 8)                        \
          : (A2b + (size_t)rgr[p] * 512 + (tc - 1) * 64 + su4[p] * 8);     \
      ra[p] = *(const uint4*)sp; } }
#define O_LDB(B, t)                                                        \
  { int tc = (t) > 8 ? 8 : (t);                                            \
    _Pragma("unroll")                                                      \
    for (int kk = 0; kk < 2; kk++) {                                       \
      int c = tc * 2 + kk;                                                 \
      B[2 * kk]     = Bq[(c * 2) * 64 + lane];                             \
      B[2 * kk + 1] = Bq[(c * 2 + 1) * 64 + lane]; } }
#define O_STA(buf, ra)                                                     \
  { _Pragma("unroll")                                                      \
    for (int p = 0; p < 2; p++) *(uint4*)&Os[buf][sph[p]] = ra[p]; }
#define O_CMP(buf, B)                                                      \
  { _Pragma("unroll")                                                      \
    for (int kk = 0; kk < 2; kk++) {                                       \
      uint4 af = *(const uint4*)&Os[buf][(wv * 16 + lrow) * 64 +           \
                                         (((kk * 4 + quad) ^ lrow) & 7) * 8]; \
      acc[0] = bmm(af, B[2 * kk], acc[0]);                                 \
      acc[1] = bmm(af, B[2 * kk + 1], acc[1]); } }

  O_LDA(rAe, 0); O_LDB(B0, 0);
  O_LDA(rAo, 1);
  O_STA(0, rAe);
  O_LDB(B1, 1);
  O_LDA(rAe, 2);
  __syncthreads();

  for (int t = 0; t < 8; t += 2) {
    O_STA(1, rAo);
    O_LDA(rAo, t + 3);
    O_CMP(0, B0);
    O_LDB(B0, t + 2);
    __syncthreads();
    O_STA(0, rAe);
    O_LDA(rAe, t + 4);
    O_CMP(1, B1);
    O_LDB(B1, t + 3);
    __syncthreads();
  }
  O_CMP(0, B0);                                   // tile 8
#undef O_LDA
#undef O_LDB
#undef O_STA
#undef O_CMP

#pragma unroll
  for (int ntl = 0; ntl < 2; ntl++) {
    int col = ntl * 16 + lrow;
    if (col < D3) {
      float bv = bias2[col];
#pragma unroll
      for (int j = 0; j < 4; j++) {
        int r = m0 + wv * 16 + quad * 4 + j;
        if (r < NN)
          out[(size_t)r * D3 + col] = acc[ntl][j] + bv;
      }
    }
  }
}

// ---------------------------------------------------------------------------
extern "C" void kernel_launch(void* const* d_in, const int* in_sizes, int n_in,
                              void* d_out, int out_size, void* d_ws,
                              size_t ws_size, hipStream_t stream) {
  const float* x_drug = (const float*)d_in[0];
  const float* drug_w = (const float*)d_in[1];
  const int*   ei     = (const int*)d_in[2];
  const float* basis1 = (const float*)d_in[3];
  const float* comp1  = (const float*)d_in[4];
  const float* root1  = (const float*)d_in[5];
  const float* bias1  = (const float*)d_in[6];
  const float* basis2 = (const float*)d_in[7];
  const float* comp2  = (const float*)d_in[8];
  const float* root2  = (const float*)d_in[9];
  const float* bias2  = (const float*)d_in[10];
  float* out = (float*)d_out;

  float* ws = (float*)d_ws;
  int*   deg  = (int*)ws;                          // 1,000,000
  int*   cnt  = deg + 1000000;                     // 10,016
  int*   off  = cnt + 10016;                       // 10,016
  int*   cur  = off + 10016;                       // 10,016
  int*   rec  = cur + 10016;                       // 500,000
  float* esc  = (float*)(rec + 500000);            // 500,000
  unsigned short* xb   = (unsigned short*)(esc + 500000);          // 640,000 f
  unsigned short* hb   = (unsigned short*)((float*)xb + 640000);   // 320,000 f
  unsigned short* Bfw  = (unsigned short*)((float*)hb + 320000);   // 131,072 f
  unsigned short* Wf1  = (unsigned short*)((float*)Bfw + 131072);  // 36,864 f
  unsigned short* Wf2  = (unsigned short*)((float*)Wf1 + 36864);   // 9,216 f
  float* R1 = (float*)Wf2 + 9216;                  // aggregation buffers
  unsigned short* A1b = (unsigned short*)R1;       // 10,000 x 1024 bf16
  unsigned short* A2b = (unsigned short*)R1;       // aliases A1b (after hlayer)

  hipMemsetAsync(deg, 0, (size_t)1000000 * 4, stream);

  // CSR build + weight prep (fused first pass)
  prep_kernel<<<(NE + W0_SZ + W1_SZ + W2_SZ + 255) / 256, 256, 0, stream>>>(
      ei, deg, drug_w, Bfw, root1, basis1, Wf1, root2, basis2, Wf2);
  cnt_kernel<<<(NN + 255) / 256, 256, 0, stream>>>(deg, cnt);
  scan_kernel<<<1, 1024, 0, stream>>>(cnt, off, cur);
  scatter_kernel<<<(NE + 255) / 256, 256, 0, stream>>>(ei, deg, cur, rec, esc);

  // x = x_drug @ drug_w
  gemm0_v5<<<(NN + 31) / 32, 256, 0, stream>>>(x_drug, Bfw, xb);

  // layer 1
  agg1e_kernel<<<(NN + 3) / 4, 256, 0, stream>>>(xb, off, rec, esc, comp1, A1b);
  hlayer_v4<<<(NN + 31) / 32, 256, 0, stream>>>(xb, A1b, Wf1, bias1, hb);

  // layer 2
  agg2e_kernel<<<(NN + 3) / 4, 256, 0, stream>>>(hb, off, rec, esc, comp2, A2b);
  out_v4<<<(NN + 31) / 32, 128, 0, stream>>>(hb, A2b, Wf2, bias2, out);
}

// Round 7
// 295.220 us; speedup vs baseline: 1.3021x; 1.0244x over previous
//
#include <hip/hip_runtime.h>

#define NN 10000    // nodes
#define RR 100      // relations
#define EE 5000     // edges per relation
#define D0 2048
#define D1 128
#define D2 64
#define D3 20
#define NE (RR*EE)  // 500000 edges total

using short8  = __attribute__((ext_vector_type(8))) short;
using float4e = __attribute__((ext_vector_type(4))) float;
using float2v = __attribute__((ext_vector_type(2))) float;

__device__ __forceinline__ unsigned short f2bf(float f) {
  unsigned int u = __float_as_uint(f);
  unsigned int r = u + 0x7fffu + ((u >> 16) & 1u);   // RNE
  return (unsigned short)(r >> 16);
}
__device__ __forceinline__ float bf2f(unsigned short u) {
  return __uint_as_float(((unsigned int)u) << 16);
}
__device__ __forceinline__ unsigned int pk2(float lo, float hi) {
  return ((unsigned int)f2bf(hi) << 16) | (unsigned int)f2bf(lo);
}
__device__ __forceinline__ float bflo(unsigned int u) {
  return __uint_as_float((u & 0xffffu) << 16);
}
__device__ __forceinline__ float bfhi(unsigned int u) {
  return __uint_as_float(u & 0xffff0000u);
}
__device__ __forceinline__ float2v mk2(float a, float b) {
  float2v v; v[0] = a; v[1] = b; return v;
}

// bf16x8 MFMA on uint4-typed fragments
__device__ __forceinline__ float4e bmm(uint4 a, uint4 b, float4e c) {
  return __builtin_amdgcn_mfma_f32_16x16x32_bf16(
      __builtin_bit_cast(short8, a), __builtin_bit_cast(short8, b), c, 0, 0, 0);
}

// ---------------------------------------------------------------------------
// fused prep: deg histogram + all three weight->bf16 fragment-layout packs
// frag element (for a 16-col tile nt): k = c*32 + (lane>>4)*8 + j,
//                                      n = nt*16 + (lane&15)
// ---------------------------------------------------------------------------
#define W0_SZ 262144   // drug_w frags: c 0..63, nt 0..7
#define W1_SZ 73728    // Wc1 frags:    c 0..35, nt 0..3
#define W2_SZ 18432    // Wc2 frags:    c 0..17, nt 0..1
__global__ void prep_kernel(const int* __restrict__ ei, int* __restrict__ deg,
                            const float* __restrict__ drug_w,
                            unsigned short* __restrict__ Bfw,
                            const float* __restrict__ root1,
                            const float* __restrict__ basis1,
                            unsigned short* __restrict__ Wf1,
                            const float* __restrict__ root2,
                            const float* __restrict__ basis2,
                            unsigned short* __restrict__ Wf2) {
  int gid = blockIdx.x * 256 + threadIdx.x;
  if (gid < NE) {
    int r = gid / EE, e = gid - r * EE;
    int d = ei[r * 2 * EE + EE + e];
    atomicAdd(&deg[r * NN + d], 1);
    return;
  }
  gid -= NE;
  if (gid < W0_SZ) {
    int j = gid & 7, lane = (gid >> 3) & 63, rest = gid >> 9;
    int nt = rest & 7, c = rest >> 3;
    int k = c * 32 + (lane >> 4) * 8 + j;
    int n = nt * 16 + (lane & 15);
    Bfw[gid] = f2bf(drug_w[(size_t)k * 128 + n]);
    return;
  }
  gid -= W0_SZ;
  if (gid < W1_SZ) {
    int j = gid & 7, lane = (gid >> 3) & 63, rest = gid >> 9;
    int nt = rest & 3, c = rest >> 2;
    int k = c * 32 + (lane >> 4) * 8 + j;
    int o = nt * 16 + (lane & 15);
    float v = (k < 128) ? root1[k * 64 + o] : basis1[(k - 128) * 64 + o];
    Wf1[gid] = f2bf(v);
    return;
  }
  gid -= W1_SZ;
  if (gid < W2_SZ) {
    int j = gid & 7, lane = (gid >> 3) & 63, rest = gid >> 9;
    int nt = rest & 1, c = rest >> 1;
    int k = c * 32 + (lane >> 4) * 8 + j;
    int cc = nt * 16 + (lane & 15);
    float v = 0.f;
    if (cc < 20) v = (k < 64) ? root2[k * 20 + cc] : basis2[(k - 64) * 20 + cc];
    Wf2[gid] = f2bf(v);
  }
}

// ---------------------------------------------------------------------------
// single-pass scan: thread t serially scans nodes [t*10, t*10+10); one
// block-scan of the 1024 thread totals; one barrier phase.
// ---------------------------------------------------------------------------
__global__ __launch_bounds__(1024) void scan_kernel(const int* __restrict__ cnt,
                                                    int* __restrict__ off,
                                                    int* __restrict__ cur) {
  __shared__ int wsum[16];
  const int tid = threadIdx.x;
  const int wv = tid >> 6, lane = tid & 63;
  const bool act = tid < 1000;
  int loc[10];
  int s = 0;
  if (act) {
#pragma unroll
    for (int i = 0; i < 10; i++) { loc[i] = cnt[tid * 10 + i]; s += loc[i]; }
  }
  int ws = s;
#pragma unroll
  for (int d = 1; d < 64; d <<= 1) {
    int t = __shfl_up(ws, d, 64);
    if (lane >= d) ws += t;
  }
  if (lane == 63) wsum[wv] = ws;
  __syncthreads();
  if (wv == 0) {
    int w = (lane < 16) ? wsum[lane] : 0;
#pragma unroll
    for (int d = 1; d < 16; d <<= 1) {
      int t = __shfl_up(w, d, 64);
      if (lane >= d) w += t;
    }
    if (lane < 16) wsum[lane] = w;
  }
  __syncthreads();
  int excl = (wv ? wsum[wv - 1] : 0) + ws - s;
  if (act) {
    int run = excl;
#pragma unroll
    for (int i = 0; i < 10; i++) {
      off[tid * 10 + i] = run;
      cur[tid * 10 + i] = run;
      run += loc[i];
    }
  }
  if (tid == 1023) off[NN] = excl;   // s==0 for tid>=1000 -> excl == total
}

// rec = (r<<14)|src, esc = 1/max(deg,1)
__global__ void scatter_kernel(const int* __restrict__ ei,
                               const int* __restrict__ deg,
                               int* __restrict__ cur, int* __restrict__ rec,
                               float* __restrict__ esc) {
  int gid = blockIdx.x * 256 + threadIdx.x;
  if (gid >= NE) return;
  int r = gid / EE, e = gid - r * EE;
  int s = ei[r * 2 * EE + e];
  int d = ei[r * 2 * EE + EE + e];
  int p = atomicAdd(&cur[d], 1);
  rec[p] = (r << 14) | s;
  esc[p] = 1.0f / fmaxf((float)deg[r * NN + d], 1.0f);
}

// ---------------------------------------------------------------------------
// gemm0cnt: blocks 0..312 = gemm0 (xb = bf16(x_drug @ drug_w), M=32, N=128,
// 4 waves, swizzled-LDS A staging, frag-layout B); blocks 313..352 = cnt
// (node total degree) -- independent work overlapped in one launch.
// ---------------------------------------------------------------------------
__global__ __launch_bounds__(256) void gemm0cnt(
    const float* __restrict__ A, const unsigned short* __restrict__ Bfw,
    unsigned short* __restrict__ xb, const int* __restrict__ deg,
    int* __restrict__ cnt) {
  if (blockIdx.x >= 313) {
    int n = (blockIdx.x - 313) * 256 + threadIdx.x;
    if (n < NN) {
      int s = 0;
      for (int r = 0; r < RR; r++) s += deg[r * NN + n];
      cnt[n] = s;
    }
    return;
  }
  __shared__ unsigned short As[2][32 * 128];
  const int tid = threadIdx.x;
  const int nw = tid >> 6, lane = tid & 63;
  const int lrow = lane & 15, quad = lane >> 4;
  const int m0 = blockIdx.x * 32;

  const int rb = tid >> 5, li = tid & 31;
  int rg[4], wo[4];
#pragma unroll
  for (int j = 0; j < 4; j++) {
    int r = rb + 8 * j;
    int g = m0 + r;
    rg[j] = g < NN ? g : NN - 1;
    wo[j] = r * 128 + (((li >> 1) ^ (r & 15)) & 15) * 8 + (li & 1) * 4;
  }

  const uint4* Bq = (const uint4*)Bfw;
  float4 rAe[4], rAo[4];
  uint4 B0[8], B1[8];
  float4e acc[2][2];
#pragma unroll
  for (int mt = 0; mt < 2; mt++)
#pragma unroll
    for (int i = 0; i < 2; i++) {
      acc[mt][i][0] = 0.f; acc[mt][i][1] = 0.f;
      acc[mt][i][2] = 0.f; acc[mt][i][3] = 0.f;
    }

#define LDA(ra, t)                                                   \
  { int tc = (t) > 15 ? 15 : (t);                                    \
    _Pragma("unroll")                                                \
    for (int j = 0; j < 4; j++)                                      \
      ra[j] = *(const float4*)(A + (size_t)rg[j] * D0 + tc * 128 + li * 4); }
#define LDB(B, t)                                                    \
  { int tc = (t) > 15 ? 15 : (t);                                    \
    _Pragma("unroll")                                                \
    for (int kk = 0; kk < 4; kk++) {                                 \
      B[2 * kk]     = Bq[((tc * 4 + kk) * 8 + 2 * nw) * 64 + lane];  \
      B[2 * kk + 1] = Bq[((tc * 4 + kk) * 8 + 2 * nw + 1) * 64 + lane]; } }
#define STA(buf, ra)                                                 \
  { _Pragma("unroll")                                                \
    for (int j = 0; j < 4; j++) {                                    \
      uint2 u; u.x = pk2(ra[j].x, ra[j].y); u.y = pk2(ra[j].z, ra[j].w); \
      *(uint2*)&As[buf][wo[j]] = u; } }
#define CMP(buf, B)                                                  \
  { _Pragma("unroll")                                                \
    for (int kk = 0; kk < 4; kk++) {                                 \
      _Pragma("unroll")                                              \
      for (int mt = 0; mt < 2; mt++) {                               \
        uint4 af = *(const uint4*)&As[buf][(mt * 16 + lrow) * 128 +  \
                                           (((kk * 4 + quad) ^ lrow) & 15) * 8]; \
        acc[mt][0] = bmm(af, B[2 * kk], acc[mt][0]);                 \
        acc[mt][1] = bmm(af, B[2 * kk + 1], acc[mt][1]); } } }

  LDA(rAe, 0); LDB(B0, 0);
  LDA(rAo, 1);
  STA(0, rAe);
  LDB(B1, 1);
  LDA(rAe, 2);
  __syncthreads();

  for (int t = 0; t < 16; t += 2) {
    STA(1, rAo);
    LDA(rAo, t + 3);
    CMP(0, B0);
    LDB(B0, t + 2);
    __syncthreads();
    STA(0, rAe);
    LDA(rAe, t + 4);
    CMP(1, B1);
    LDB(B1, t + 3);
    __syncthreads();
  }
#undef LDA
#undef LDB
#undef STA
#undef CMP

  const int c0 = nw * 32 + lrow;
#pragma unroll
  for (int mt = 0; mt < 2; mt++) {
#pragma unroll
    for (int j = 0; j < 4; j++) {
      int r = m0 + mt * 16 + quad * 4 + j;
      if (r < NN) {
        xb[(size_t)r * D1 + c0]      = f2bf(acc[mt][0][j]);
        xb[(size_t)r * D1 + c0 + 16] = f2bf(acc[mt][1][j]);
      }
    }
  }
}

// ---------------------------------------------------------------------------
// agg1e: A1b[n, b*128+i] = bf16( sum_{e->n} esc_e*comp1[r_e,b]*x[src_e,i] )
// one wave per node; lane holds 2 of 128 channels; 8-edge unroll;
// packed fp32 FMA (float2 acc) -> v_pk_fma_f32; sc*x factored.
// ---------------------------------------------------------------------------
__global__ __launch_bounds__(256) void agg1e_kernel(
    const unsigned short* __restrict__ xb, const int* __restrict__ off,
    const int* __restrict__ rec, const float* __restrict__ esc,
    const float* __restrict__ comp, unsigned short* __restrict__ A1b) {
  __shared__ float s_comp[RR * 8];
  const int tid = threadIdx.x;
  for (int i = tid; i < RR * 8; i += 256) s_comp[i] = comp[i];
  __syncthreads();
  const int wv = tid >> 6, lane = tid & 63;
  const int n = blockIdx.x * 4 + wv;
  if (n >= NN) return;
  float2v acc[8];
#pragma unroll
  for (int b = 0; b < 8; b++) { acc[b][0] = 0.f; acc[b][1] = 0.f; }
  const int beg = off[n], end = off[n + 1];
  int idx = beg;
  for (; idx + 7 < end; idx += 8) {
    int rc[8]; float sc[8]; unsigned int xv[8];
#pragma unroll
    for (int u = 0; u < 8; u++) {
      rc[u] = rec[idx + u];
      sc[u] = esc[idx + u];
    }
#pragma unroll
    for (int u = 0; u < 8; u++)
      xv[u] = *(const unsigned int*)&xb[(size_t)(rc[u] & 16383) * D1 + lane * 2];
#pragma unroll
    for (int u = 0; u < 8; u++) {
      const float* cb = &s_comp[(rc[u] >> 14) * 8];
      float2v sx = mk2(sc[u] * bflo(xv[u]), sc[u] * bfhi(xv[u]));
#pragma unroll
      for (int b = 0; b < 8; b++)
        acc[b] = __builtin_elementwise_fma(mk2(cb[b], cb[b]), sx, acc[b]);
    }
  }
  for (; idx < end; idx++) {
    int rc = rec[idx];
    float sc = esc[idx];
    unsigned int xv = *(const unsigned int*)&xb[(size_t)(rc & 16383) * D1 + lane * 2];
    const float* cb = &s_comp[(rc >> 14) * 8];
    float2v sx = mk2(sc * bflo(xv), sc * bfhi(xv));
#pragma unroll
    for (int b = 0; b < 8; b++)
      acc[b] = __builtin_elementwise_fma(mk2(cb[b], cb[b]), sx, acc[b]);
  }
#pragma unroll
  for (int b = 0; b < 8; b++) {
    ushort2 o; o.x = f2bf(acc[b][0]); o.y = f2bf(acc[b][1]);
    *(ushort2*)&A1b[(size_t)n * 1024 + b * 128 + lane * 2] = o;
  }
}

// ---------------------------------------------------------------------------
// agg2e: TWO nodes per wave (half-wave per node; lane covers 2 of 64 ch via
// 4B loads -> 256B/wave-iter across 2 rows). acc[8] float2 = 16 regs.
// Wave-uniform 4-edge unrolled main loop to min(cntA,cntB), per-lane tail.
// ---------------------------------------------------------------------------
__global__ __launch_bounds__(256) void agg2e_kernel(
    const unsigned short* __restrict__ hb, const int* __restrict__ off,
    const int* __restrict__ rec, const float* __restrict__ esc,
    const float* __restrict__ comp, unsigned short* __restrict__ A2b) {
  __shared__ float s_comp[RR * 8];
  const int tid = threadIdx.x;
  for (int i = tid; i < RR * 8; i += 256) s_comp[i] = comp[i];
  __syncthreads();
  const int wv = tid >> 6, lane = tid & 63;
  const int half = lane >> 5, li = lane & 31;
  const int n = blockIdx.x * 8 + wv * 2 + half;    // 1250*8 == 10000 exact
  const int beg = off[n], end = off[n + 1];
  const int cnt = end - beg;
  const int cother = __shfl_xor(cnt, 32);
  const int mmin = (cnt < cother ? cnt : cother) & ~3;

  float2v acc[8];
#pragma unroll
  for (int b = 0; b < 8; b++) { acc[b][0] = 0.f; acc[b][1] = 0.f; }

  int e = beg;
  for (int it = 0; it < mmin; it += 4, e += 4) {
    int rc[4]; float sc[4]; unsigned int hv[4];
#pragma unroll
    for (int u = 0; u < 4; u++) {
      rc[u] = rec[e + u];
      sc[u] = esc[e + u];
    }
#pragma unroll
    for (int u = 0; u < 4; u++)
      hv[u] = *(const unsigned int*)&hb[(size_t)(rc[u] & 16383) * D2 + li * 2];
#pragma unroll
    for (int u = 0; u < 4; u++) {
      const float* cb = &s_comp[(rc[u] >> 14) * 8];
      float2v sh = mk2(sc[u] * bflo(hv[u]), sc[u] * bfhi(hv[u]));
#pragma unroll
      for (int b = 0; b < 8; b++)
        acc[b] = __builtin_elementwise_fma(mk2(cb[b], cb[b]), sh, acc[b]);
    }
  }
  for (; e < end; e++) {
    int rc = rec[e];
    float sc = esc[e];
    unsigned int hv = *(const unsigned int*)&hb[(size_t)(rc & 16383) * D2 + li * 2];
    const float* cb = &s_comp[(rc >> 14) * 8];
    float2v sh = mk2(sc * bflo(hv), sc * bfhi(hv));
#pragma unroll
    for (int b = 0; b < 8; b++)
      acc[b] = __builtin_elementwise_fma(mk2(cb[b], cb[b]), sh, acc[b]);
  }
#pragma unroll
  for (int b = 0; b < 8; b++) {
    ushort2 o; o.x = f2bf(acc[b][0]); o.y = f2bf(acc[b][1]);
    *(ushort2*)&A2b[(size_t)n * 512 + b * 64 + li * 2] = o;
  }
}

// ---------------------------------------------------------------------------
// hlayer_v4: hb = bf16(relu([xb|A1b](K=1152) @ Wc1 + bias1))
// M=32 (313 blocks), N=64, 4 waves. A staged coalesced bf16 -> swizzled LDS;
// 9 K-tiles of 128. B direct frag-layout.
// ---------------------------------------------------------------------------
__global__ __launch_bounds__(256) void hlayer_v4(
    const unsigned short* __restrict__ xb, const unsigned short* __restrict__ A1b,
    const unsigned short* __restrict__ Wf, const float* __restrict__ bias1,
    unsigned short* __restrict__ hb) {
  __shared__ unsigned short Hs[2][32 * 128];
  const int tid = threadIdx.x;
  const int wv = tid >> 6, lane = tid & 63;
  const int lrow = lane & 15, quad = lane >> 4;
  const int m0 = blockIdx.x * 32;
  const int mt = wv >> 1, nb = (wv & 1) * 2;

  int rgr[2], su4[2], sph[2];
#pragma unroll
  for (int p = 0; p < 2; p++) {
    int idx = tid + p * 256;
    int r = idx >> 4, u = idx & 15;
    int g = m0 + r;
    rgr[p] = g < NN ? g : NN - 1;
    su4[p] = u;
    sph[p] = r * 128 + ((u ^ (r & 15)) & 15) * 8;
  }

  const uint4* Bq = (const uint4*)Wf;
  uint4 rAe[2], rAo[2];
  uint4 B0[8], B1[8];
  float4e acc[2];
#pragma unroll
  for (int i = 0; i < 2; i++) {
    acc[i][0] = 0.f; acc[i][1] = 0.f; acc[i][2] = 0.f; acc[i][3] = 0.f;
  }

#define H_LDA(ra, t)                                                       \
  { int tc = (t) > 8 ? 8 : (t);                                            \
    _Pragma("unroll")                                                      \
    for (int p = 0; p < 2; p++) {                                          \
      const unsigned short* sp = (tc == 0)                                 \
          ? (xb + (size_t)rgr[p] * D1 + su4[p] * 8)                        \
          : (A1b + (size_t)rgr[p] * 1024 + (tc - 1) * 128 + su4[p] * 8);   \
      ra[p] = *(const uint4*)sp; } }
#define H_LDB(B, t)                                                        \
  { int tc = (t) > 8 ? 8 : (t);                                            \
    _Pragma("unroll")                                                      \
    for (int kk = 0; kk < 4; kk++) {                                       \
      int c = tc * 4 + kk;                                                 \
      B[2 * kk]     = Bq[(c * 4 + nb) * 64 + lane];                        \
      B[2 * kk + 1] = Bq[(c * 4 + nb + 1) * 64 + lane]; } }
#define H_STA(buf, ra)                                                     \
  { _Pragma("unroll")                                                      \
    for (int p = 0; p < 2; p++) *(uint4*)&Hs[buf][sph[p]] = ra[p]; }
#define H_CMP(buf, B)                                                      \
  { _Pragma("unroll")                                                      \
    for (int kk = 0; kk < 4; kk++) {                                       \
      uint4 af = *(const uint4*)&Hs[buf][(mt * 16 + lrow) * 128 +          \
                                         (((kk * 4 + quad) ^ lrow) & 15) * 8]; \
      acc[0] = bmm(af, B[2 * kk], acc[0]);                                 \
      acc[1] = bmm(af, B[2 * kk + 1], acc[1]); } }

  H_LDA(rAe, 0); H_LDB(B0, 0);
  H_LDA(rAo, 1);
  H_STA(0, rAe);
  H_LDB(B1, 1);
  H_LDA(rAe, 2);
  __syncthreads();

  for (int t = 0; t < 8; t += 2) {
    H_STA(1, rAo);
    H_LDA(rAo, t + 3);
    H_CMP(0, B0);
    H_LDB(B0, t + 2);
    __syncthreads();
    H_STA(0, rAe);
    H_LDA(rAe, t + 4);
    H_CMP(1, B1);
    H_LDB(B1, t + 3);
    __syncthreads();
  }
  H_CMP(0, B0);                                   // tile 8
#undef H_LDA
#undef H_LDB
#undef H_STA
#undef H_CMP

#pragma unroll
  for (int ntl = 0; ntl < 2; ntl++) {
    int col = (nb + ntl) * 16 + lrow;
    float bv = bias1[col];
#pragma unroll
    for (int j = 0; j < 4; j++) {
      int r = m0 + mt * 16 + quad * 4 + j;
      if (r < NN)
        hb[(size_t)r * D2 + col] = f2bf(fmaxf(acc[ntl][j] + bv, 0.f));
    }
  }
}

// ---------------------------------------------------------------------------
// out_v4: out = [hb|A2b](K=576) @ Wc2 + bias2
// ---------------------------------------------------------------------------
__global__ __launch_bounds__(128) void out_v4(
    const unsigned short* __restrict__ hb, const unsigned short* __restrict__ A2b,
    const unsigned short* __restrict__ Wf, const float* __restrict__ bias2,
    float* __restrict__ out) {
  __shared__ unsigned short Os[2][32 * 64];
  const int tid = threadIdx.x;
  const int wv = tid >> 6, lane = tid & 63;
  const int lrow = lane & 15, quad = lane >> 4;
  const int m0 = blockIdx.x * 32;

  int rgr[2], su4[2], sph[2];
#pragma unroll
  for (int p = 0; p < 2; p++) {
    int idx = tid + p * 128;
    int r = idx >> 3, u = idx & 7;
    int g = m0 + r;
    rgr[p] = g < NN ? g : NN - 1;
    su4[p] = u;
    sph[p] = r * 64 + ((u ^ (r & 7)) & 7) * 8;
  }

  const uint4* Bq = (const uint4*)Wf;
  uint4 rAe[2], rAo[2];
  uint4 B0[4], B1[4];
  float4e acc[2];
#pragma unroll
  for (int i = 0; i < 2; i++) {
    acc[i][0] = 0.f; acc[i][1] = 0.f; acc[i][2] = 0.f; acc[i][3] = 0.f;
  }

#define O_LDA(ra, t)                                                       \
  { int tc = (t) > 8 ? 8 : (t);                                            \
    _Pragma("unroll")                                                      \
    for (int p = 0; p < 2; p++) {                                          \
      const unsigned short* sp = (tc == 0)                                 \
          ? (hb + (size_t)rgr[p] * D2 + su4[p] * 8)                        \
          : (A2b + (size_t)rgr[p] * 512 + (tc - 1) * 64 + su4[p] * 8);     \
      ra[p] = *(const uint4*)sp; } }
#define O_LDB(B, t)                                                        \
  { int tc = (t) > 8 ? 8 : (t);                                            \
    _Pragma("unroll")                                                      \
    for (int kk = 0; kk < 2; kk++) {                                       \
      int c = tc * 2 + kk;                                                 \
      B[2 * kk]     = Bq[(c * 2) * 64 + lane];                             \
      B[2 * kk + 1] = Bq[(c * 2 + 1) * 64 + lane]; } }
#define O_STA(buf, ra)                                                     \
  { _Pragma("unroll")                                                      \
    for (int p = 0; p < 2; p++) *(uint4*)&Os[buf][sph[p]] = ra[p]; }
#define O_CMP(buf, B)                                                      \
  { _Pragma("unroll")                                                      \
    for (int kk = 0; kk < 2; kk++) {                                       \
      uint4 af = *(const uint4*)&Os[buf][(wv * 16 + lrow) * 64 +           \
                                         (((kk * 4 + quad) ^ lrow) & 7) * 8]; \
      acc[0] = bmm(af, B[2 * kk], acc[0]);                                 \
      acc[1] = bmm(af, B[2 * kk + 1], acc[1]); } }

  O_LDA(rAe, 0); O_LDB(B0, 0);
  O_LDA(rAo, 1);
  O_STA(0, rAe);
  O_LDB(B1, 1);
  O_LDA(rAe, 2);
  __syncthreads();

  for (int t = 0; t < 8; t += 2) {
    O_STA(1, rAo);
    O_LDA(rAo, t + 3);
    O_CMP(0, B0);
    O_LDB(B0, t + 2);
    __syncthreads();
    O_STA(0, rAe);
    O_LDA(rAe, t + 4);
    O_CMP(1, B1);
    O_LDB(B1, t + 3);
    __syncthreads();
  }
  O_CMP(0, B0);                                   // tile 8
#undef O_LDA
#undef O_LDB
#undef O_STA
#undef O_CMP

#pragma unroll
  for (int ntl = 0; ntl < 2; ntl++) {
    int col = ntl * 16 + lrow;
    if (col < D3) {
      float bv = bias2[col];
#pragma unroll
      for (int j = 0; j < 4; j++) {
        int r = m0 + wv * 16 + quad * 4 + j;
        if (r < NN)
          out[(size_t)r * D3 + col] = acc[ntl][j] + bv;
      }
    }
  }
}

// ---------------------------------------------------------------------------
extern "C" void kernel_launch(void* const* d_in, const int* in_sizes, int n_in,
                              void* d_out, int out_size, void* d_ws,
                              size_t ws_size, hipStream_t stream) {
  const float* x_drug = (const float*)d_in[0];
  const float* drug_w = (const float*)d_in[1];
  const int*   ei     = (const int*)d_in[2];
  const float* basis1 = (const float*)d_in[3];
  const float* comp1  = (const float*)d_in[4];
  const float* root1  = (const float*)d_in[5];
  const float* bias1  = (const float*)d_in[6];
  const float* basis2 = (const float*)d_in[7];
  const float* comp2  = (const float*)d_in[8];
  const float* root2  = (const float*)d_in[9];
  const float* bias2  = (const float*)d_in[10];
  float* out = (float*)d_out;

  float* ws = (float*)d_ws;
  int*   deg  = (int*)ws;                          // 1,000,000
  int*   cnt  = deg + 1000000;                     // 10,016
  int*   off  = cnt + 10016;                       // 10,016
  int*   cur  = off + 10016;                       // 10,016
  int*   rec  = cur + 10016;                       // 500,000
  float* esc  = (float*)(rec + 500000);            // 500,000
  unsigned short* xb   = (unsigned short*)(esc + 500000);          // 640,000 f
  unsigned short* hb   = (unsigned short*)((float*)xb + 640000);   // 320,000 f
  unsigned short* Bfw  = (unsigned short*)((float*)hb + 320000);   // 131,072 f
  unsigned short* Wf1  = (unsigned short*)((float*)Bfw + 131072);  // 36,864 f
  unsigned short* Wf2  = (unsigned short*)((float*)Wf1 + 36864);   // 9,216 f
  float* R1 = (float*)Wf2 + 9216;                  // aggregation buffers
  unsigned short* A1b = (unsigned short*)R1;       // 10,000 x 1024 bf16
  unsigned short* A2b = (unsigned short*)R1;       // aliases A1b (after hlayer)

  hipMemsetAsync(deg, 0, (size_t)1000000 * 4, stream);

  // CSR build + weight prep (fused first pass)
  prep_kernel<<<(NE + W0_SZ + W1_SZ + W2_SZ + 255) / 256, 256, 0, stream>>>(
      ei, deg, drug_w, Bfw, root1, basis1, Wf1, root2, basis2, Wf2);

  // gemm0 (needs Bfw) overlapped with cnt (needs deg) -- both from prep
  gemm0cnt<<<313 + 40, 256, 0, stream>>>(x_drug, Bfw, xb, deg, cnt);

  scan_kernel<<<1, 1024, 0, stream>>>(cnt, off, cur);
  scatter_kernel<<<(NE + 255) / 256, 256, 0, stream>>>(ei, deg, cur, rec, esc);

  // layer 1
  agg1e_kernel<<<(NN + 3) / 4, 256, 0, stream>>>(xb, off, rec, esc, comp1, A1b);
  hlayer_v4<<<(NN + 31) / 32, 256, 0, stream>>>(xb, A1b, Wf1, bias1, hb);

  // layer 2
  agg2e_kernel<<<NN / 8, 256, 0, stream>>>(hb, off, rec, esc, comp2, A2b);
  out_v4<<<(NN + 31) / 32, 128, 0, stream>>>(hb, A2b, Wf2, bias2, out);
}

// Round 8
// 285.309 us; speedup vs baseline: 1.3473x; 1.0347x over previous
//
#include <hip/hip_runtime.h>

#define NN 10000    // nodes
#define RR 100      // relations
#define EE 5000     // edges per relation
#define D0 2048
#define D1 128
#define D2 64
#define D3 20
#define NE (RR*EE)  // 500000 edges total

using short8  = __attribute__((ext_vector_type(8))) short;
using float4e = __attribute__((ext_vector_type(4))) float;
using float2v = __attribute__((ext_vector_type(2))) float;

__device__ __forceinline__ unsigned short f2bf(float f) {
  unsigned int u = __float_as_uint(f);
  unsigned int r = u + 0x7fffu + ((u >> 16) & 1u);   // RNE
  return (unsigned short)(r >> 16);
}
__device__ __forceinline__ float bf2f(unsigned short u) {
  return __uint_as_float(((unsigned int)u) << 16);
}
__device__ __forceinline__ unsigned int pk2(float lo, float hi) {
  return ((unsigned int)f2bf(hi) << 16) | (unsigned int)f2bf(lo);
}
__device__ __forceinline__ float bflo(unsigned int u) {
  return __uint_as_float((u & 0xffffu) << 16);
}
__device__ __forceinline__ float bfhi(unsigned int u) {
  return __uint_as_float(u & 0xffff0000u);
}
__device__ __forceinline__ float2v mk2(float a, float b) {
  float2v v; v[0] = a; v[1] = b; return v;
}

// bf16x8 MFMA on uint4-typed fragments
__device__ __forceinline__ float4e bmm(uint4 a, uint4 b, float4e c) {
  return __builtin_amdgcn_mfma_f32_16x16x32_bf16(
      __builtin_bit_cast(short8, a), __builtin_bit_cast(short8, b), c, 0, 0, 0);
}

// ---------------------------------------------------------------------------
// fused prep: deg histogram + all three weight->bf16 fragment-layout packs
// ---------------------------------------------------------------------------
#define W0_SZ 262144   // drug_w frags: c 0..63, nt 0..7
#define W1_SZ 73728    // Wc1 frags:    c 0..35, nt 0..3
#define W2_SZ 18432    // Wc2 frags:    c 0..17, nt 0..1
__global__ void prep_kernel(const int* __restrict__ ei, int* __restrict__ deg,
                            const float* __restrict__ drug_w,
                            unsigned short* __restrict__ Bfw,
                            const float* __restrict__ root1,
                            const float* __restrict__ basis1,
                            unsigned short* __restrict__ Wf1,
                            const float* __restrict__ root2,
                            const float* __restrict__ basis2,
                            unsigned short* __restrict__ Wf2) {
  int gid = blockIdx.x * 256 + threadIdx.x;
  if (gid < NE) {
    int r = gid / EE, e = gid - r * EE;
    int d = ei[r * 2 * EE + EE + e];
    atomicAdd(&deg[r * NN + d], 1);
    return;
  }
  gid -= NE;
  if (gid < W0_SZ) {
    int j = gid & 7, lane = (gid >> 3) & 63, rest = gid >> 9;
    int nt = rest & 7, c = rest >> 3;
    int k = c * 32 + (lane >> 4) * 8 + j;
    int n = nt * 16 + (lane & 15);
    Bfw[gid] = f2bf(drug_w[(size_t)k * 128 + n]);
    return;
  }
  gid -= W0_SZ;
  if (gid < W1_SZ) {
    int j = gid & 7, lane = (gid >> 3) & 63, rest = gid >> 9;
    int nt = rest & 3, c = rest >> 2;
    int k = c * 32 + (lane >> 4) * 8 + j;
    int o = nt * 16 + (lane & 15);
    float v = (k < 128) ? root1[k * 64 + o] : basis1[(k - 128) * 64 + o];
    Wf1[gid] = f2bf(v);
    return;
  }
  gid -= W1_SZ;
  if (gid < W2_SZ) {
    int j = gid & 7, lane = (gid >> 3) & 63, rest = gid >> 9;
    int nt = rest & 1, c = rest >> 1;
    int k = c * 32 + (lane >> 4) * 8 + j;
    int cc = nt * 16 + (lane & 15);
    float v = 0.f;
    if (cc < 20) v = (k < 64) ? root2[k * 20 + cc] : basis2[(k - 64) * 20 + cc];
    Wf2[gid] = f2bf(v);
  }
}

// ---------------------------------------------------------------------------
// single-pass scan
// ---------------------------------------------------------------------------
__global__ __launch_bounds__(1024) void scan_kernel(const int* __restrict__ cnt,
                                                    int* __restrict__ off,
                                                    int* __restrict__ cur) {
  __shared__ int wsum[16];
  const int tid = threadIdx.x;
  const int wv = tid >> 6, lane = tid & 63;
  const bool act = tid < 1000;
  int loc[10];
  int s = 0;
  if (act) {
#pragma unroll
    for (int i = 0; i < 10; i++) { loc[i] = cnt[tid * 10 + i]; s += loc[i]; }
  }
  int ws = s;
#pragma unroll
  for (int d = 1; d < 64; d <<= 1) {
    int t = __shfl_up(ws, d, 64);
    if (lane >= d) ws += t;
  }
  if (lane == 63) wsum[wv] = ws;
  __syncthreads();
  if (wv == 0) {
    int w = (lane < 16) ? wsum[lane] : 0;
#pragma unroll
    for (int d = 1; d < 16; d <<= 1) {
      int t = __shfl_up(w, d, 64);
      if (lane >= d) w += t;
    }
    if (lane < 16) wsum[lane] = w;
  }
  __syncthreads();
  int excl = (wv ? wsum[wv - 1] : 0) + ws - s;
  if (act) {
    int run = excl;
#pragma unroll
    for (int i = 0; i < 10; i++) {
      off[tid * 10 + i] = run;
      cur[tid * 10 + i] = run;
      run += loc[i];
    }
  }
  if (tid == 1023) off[NN] = excl;   // s==0 for tid>=1000 -> excl == total
}

// re[p] = { (r<<14)|src , bits(1/max(deg,1)) }  -- one 8B record per edge
__global__ void scatter_kernel(const int* __restrict__ ei,
                               const int* __restrict__ deg,
                               int* __restrict__ cur, int2* __restrict__ re) {
  int gid = blockIdx.x * 256 + threadIdx.x;
  if (gid >= NE) return;
  int r = gid / EE, e = gid - r * EE;
  int s = ei[r * 2 * EE + e];
  int d = ei[r * 2 * EE + EE + e];
  int p = atomicAdd(&cur[d], 1);
  float escv = 1.0f / fmaxf((float)deg[r * NN + d], 1.0f);
  re[p] = make_int2((r << 14) | s, __float_as_int(escv));
}

// ---------------------------------------------------------------------------
// gemm0cnt: blocks 0..312 = gemm0 (M=32, N=128); blocks 313..352 = cnt
// ---------------------------------------------------------------------------
__global__ __launch_bounds__(256) void gemm0cnt(
    const float* __restrict__ A, const unsigned short* __restrict__ Bfw,
    unsigned short* __restrict__ xb, const int* __restrict__ deg,
    int* __restrict__ cnt) {
  if (blockIdx.x >= 313) {
    int n = (blockIdx.x - 313) * 256 + threadIdx.x;
    if (n < NN) {
      int s = 0;
      for (int r = 0; r < RR; r++) s += deg[r * NN + n];
      cnt[n] = s;
    }
    return;
  }
  __shared__ unsigned short As[2][32 * 128];
  const int tid = threadIdx.x;
  const int nw = tid >> 6, lane = tid & 63;
  const int lrow = lane & 15, quad = lane >> 4;
  const int m0 = blockIdx.x * 32;

  const int rb = tid >> 5, li = tid & 31;
  int rg[4], wo[4];
#pragma unroll
  for (int j = 0; j < 4; j++) {
    int r = rb + 8 * j;
    int g = m0 + r;
    rg[j] = g < NN ? g : NN - 1;
    wo[j] = r * 128 + (((li >> 1) ^ (r & 15)) & 15) * 8 + (li & 1) * 4;
  }

  const uint4* Bq = (const uint4*)Bfw;
  float4 rAe[4], rAo[4];
  uint4 B0[8], B1[8];
  float4e acc[2][2];
#pragma unroll
  for (int mt = 0; mt < 2; mt++)
#pragma unroll
    for (int i = 0; i < 2; i++) {
      acc[mt][i][0] = 0.f; acc[mt][i][1] = 0.f;
      acc[mt][i][2] = 0.f; acc[mt][i][3] = 0.f;
    }

#define LDA(ra, t)                                                   \
  { int tc = (t) > 15 ? 15 : (t);                                    \
    _Pragma("unroll")                                                \
    for (int j = 0; j < 4; j++)                                      \
      ra[j] = *(const float4*)(A + (size_t)rg[j] * D0 + tc * 128 + li * 4); }
#define LDB(B, t)                                                    \
  { int tc = (t) > 15 ? 15 : (t);                                    \
    _Pragma("unroll")                                                \
    for (int kk = 0; kk < 4; kk++) {                                 \
      B[2 * kk]     = Bq[((tc * 4 + kk) * 8 + 2 * nw) * 64 + lane];  \
      B[2 * kk + 1] = Bq[((tc * 4 + kk) * 8 + 2 * nw + 1) * 64 + lane]; } }
#define STA(buf, ra)                                                 \
  { _Pragma("unroll")                                                \
    for (int j = 0; j < 4; j++) {                                    \
      uint2 u; u.x = pk2(ra[j].x, ra[j].y); u.y = pk2(ra[j].z, ra[j].w); \
      *(uint2*)&As[buf][wo[j]] = u; } }
#define CMP(buf, B)                                                  \
  { _Pragma("unroll")                                                \
    for (int kk = 0; kk < 4; kk++) {                                 \
      _Pragma("unroll")                                              \
      for (int mt = 0; mt < 2; mt++) {                               \
        uint4 af = *(const uint4*)&As[buf][(mt * 16 + lrow) * 128 +  \
                                           (((kk * 4 + quad) ^ lrow) & 15) * 8]; \
        acc[mt][0] = bmm(af, B[2 * kk], acc[mt][0]);                 \
        acc[mt][1] = bmm(af, B[2 * kk + 1], acc[mt][1]); } } }

  LDA(rAe, 0); LDB(B0, 0);
  LDA(rAo, 1);
  STA(0, rAe);
  LDB(B1, 1);
  LDA(rAe, 2);
  __syncthreads();

  for (int t = 0; t < 16; t += 2) {
    STA(1, rAo);
    LDA(rAo, t + 3);
    CMP(0, B0);
    LDB(B0, t + 2);
    __syncthreads();
    STA(0, rAe);
    LDA(rAe, t + 4);
    CMP(1, B1);
    LDB(B1, t + 3);
    __syncthreads();
  }
#undef LDA
#undef LDB
#undef STA
#undef CMP

  const int c0 = nw * 32 + lrow;
#pragma unroll
  for (int mt = 0; mt < 2; mt++) {
#pragma unroll
    for (int j = 0; j < 4; j++) {
      int r = m0 + mt * 16 + quad * 4 + j;
      if (r < NN) {
        xb[(size_t)r * D1 + c0]      = f2bf(acc[mt][0][j]);
        xb[(size_t)r * D1 + c0 + 16] = f2bf(acc[mt][1][j]);
      }
    }
  }
}

// ---------------------------------------------------------------------------
// agg1e: A1b[n, b*128+i] = bf16( sum_{e->n} esc_e*comp1[r_e,b]*x[src_e,i] )
// one wave per node; all control data (re records, comp rows) is wave-uniform
// and forced to SGPR via readfirstlane -> s_load path; vector pipe carries
// only the per-lane gather + FMAs. No LDS, no barrier.
// ---------------------------------------------------------------------------
__global__ __launch_bounds__(256) void agg1e_kernel(
    const unsigned short* __restrict__ xb, const int* __restrict__ off,
    const int2* __restrict__ re, const float* __restrict__ comp,
    unsigned short* __restrict__ A1b) {
  const int tid = threadIdx.x;
  const int wv = tid >> 6, lane = tid & 63;
  const int n = blockIdx.x * 4 + wv;
  if (n >= NN) return;
  float2v acc[8];
#pragma unroll
  for (int b = 0; b < 8; b++) { acc[b][0] = 0.f; acc[b][1] = 0.f; }
  const int beg = __builtin_amdgcn_readfirstlane(off[n]);
  const int end = __builtin_amdgcn_readfirstlane(off[n + 1]);
  int idx = beg;
  for (; idx + 7 < end; idx += 8) {
    int rc[8]; float sc[8]; unsigned int xv[8];
#pragma unroll
    for (int u = 0; u < 8; u++) {
      int2 t = re[idx + u];
      rc[u] = __builtin_amdgcn_readfirstlane(t.x);
      sc[u] = __uint_as_float(__builtin_amdgcn_readfirstlane(t.y));
    }
#pragma unroll
    for (int u = 0; u < 8; u++)
      xv[u] = *(const unsigned int*)&xb[(size_t)(rc[u] & 16383) * D1 + lane * 2];
#pragma unroll
    for (int u = 0; u < 8; u++) {
      const float* cb = &comp[(rc[u] >> 14) * 8];
      float2v sx = mk2(sc[u] * bflo(xv[u]), sc[u] * bfhi(xv[u]));
#pragma unroll
      for (int b = 0; b < 8; b++)
        acc[b] = __builtin_elementwise_fma(mk2(cb[b], cb[b]), sx, acc[b]);
    }
  }
  for (; idx < end; idx++) {
    int2 t = re[idx];
    int rc = __builtin_amdgcn_readfirstlane(t.x);
    float sc = __uint_as_float(__builtin_amdgcn_readfirstlane(t.y));
    unsigned int xv = *(const unsigned int*)&xb[(size_t)(rc & 16383) * D1 + lane * 2];
    const float* cb = &comp[(rc >> 14) * 8];
    float2v sx = mk2(sc * bflo(xv), sc * bfhi(xv));
#pragma unroll
    for (int b = 0; b < 8; b++)
      acc[b] = __builtin_elementwise_fma(mk2(cb[b], cb[b]), sx, acc[b]);
  }
#pragma unroll
  for (int b = 0; b < 8; b++) {
    ushort2 o; o.x = f2bf(acc[b][0]); o.y = f2bf(acc[b][1]);
    *(ushort2*)&A1b[(size_t)n * 1024 + b * 128 + lane * 2] = o;
  }
}

// ---------------------------------------------------------------------------
// agg2e: one wave per node; lane holds 1 of 64 channels (full 128B row per
// gather); same scalarized uniform-load structure; acc[8]=8 regs.
// ---------------------------------------------------------------------------
__global__ __launch_bounds__(256) void agg2e_kernel(
    const unsigned short* __restrict__ hb, const int* __restrict__ off,
    const int2* __restrict__ re, const float* __restrict__ comp,
    unsigned short* __restrict__ A2b) {
  const int tid = threadIdx.x;
  const int wv = tid >> 6, lane = tid & 63;
  const int n = blockIdx.x * 4 + wv;
  if (n >= NN) return;
  float acc[8];
#pragma unroll
  for (int b = 0; b < 8; b++) acc[b] = 0.f;
  const int beg = __builtin_amdgcn_readfirstlane(off[n]);
  const int end = __builtin_amdgcn_readfirstlane(off[n + 1]);
  int idx = beg;
  for (; idx + 7 < end; idx += 8) {
    int rc[8]; float sc[8]; float hv[8];
#pragma unroll
    for (int u = 0; u < 8; u++) {
      int2 t = re[idx + u];
      rc[u] = __builtin_amdgcn_readfirstlane(t.x);
      sc[u] = __uint_as_float(__builtin_amdgcn_readfirstlane(t.y));
    }
#pragma unroll
    for (int u = 0; u < 8; u++)
      hv[u] = bf2f(hb[(size_t)(rc[u] & 16383) * D2 + lane]);
#pragma unroll
    for (int u = 0; u < 8; u++) {
      const float* cb = &comp[(rc[u] >> 14) * 8];
      float sh = sc[u] * hv[u];
#pragma unroll
      for (int b = 0; b < 8; b++) acc[b] = fmaf(cb[b], sh, acc[b]);
    }
  }
  for (; idx < end; idx++) {
    int2 t = re[idx];
    int rc = __builtin_amdgcn_readfirstlane(t.x);
    float sc = __uint_as_float(__builtin_amdgcn_readfirstlane(t.y));
    float hv = bf2f(hb[(size_t)(rc & 16383) * D2 + lane]);
    const float* cb = &comp[(rc >> 14) * 8];
    float sh = sc * hv;
#pragma unroll
    for (int b = 0; b < 8; b++) acc[b] = fmaf(cb[b], sh, acc[b]);
  }
#pragma unroll
  for (int b = 0; b < 8; b++)
    A2b[(size_t)n * 512 + b * 64 + lane] = f2bf(acc[b]);
}

// ---------------------------------------------------------------------------
// hlayer_v4: hb = bf16(relu([xb|A1b](K=1152) @ Wc1 + bias1))
// ---------------------------------------------------------------------------
__global__ __launch_bounds__(256) void hlayer_v4(
    const unsigned short* __restrict__ xb, const unsigned short* __restrict__ A1b,
    const unsigned short* __restrict__ Wf, const float* __restrict__ bias1,
    unsigned short* __restrict__ hb) {
  __shared__ unsigned short Hs[2][32 * 128];
  const int tid = threadIdx.x;
  const int wv = tid >> 6, lane = tid & 63;
  const int lrow = lane & 15, quad = lane >> 4;
  const int m0 = blockIdx.x * 32;
  const int mt = wv >> 1, nb = (wv & 1) * 2;

  int rgr[2], su4[2], sph[2];
#pragma unroll
  for (int p = 0; p < 2; p++) {
    int idx = tid + p * 256;
    int r = idx >> 4, u = idx & 15;
    int g = m0 + r;
    rgr[p] = g < NN ? g : NN - 1;
    su4[p] = u;
    sph[p] = r * 128 + ((u ^ (r & 15)) & 15) * 8;
  }

  const uint4* Bq = (const uint4*)Wf;
  uint4 rAe[2], rAo[2];
  uint4 B0[8], B1[8];
  float4e acc[2];
#pragma unroll
  for (int i = 0; i < 2; i++) {
    acc[i][0] = 0.f; acc[i][1] = 0.f; acc[i][2] = 0.f; acc[i][3] = 0.f;
  }

#define H_LDA(ra, t)                                                       \
  { int tc = (t) > 8 ? 8 : (t);                                            \
    _Pragma("unroll")                                                      \
    for (int p = 0; p < 2; p++) {                                          \
      const unsigned short* sp = (tc == 0)                                 \
          ? (xb + (size_t)rgr[p] * D1 + su4[p] * 8)                        \
          : (A1b + (size_t)rgr[p] * 1024 + (tc - 1) * 128 + su4[p] * 8);   \
      ra[p] = *(const uint4*)sp; } }
#define H_LDB(B, t)                                                        \
  { int tc = (t) > 8 ? 8 : (t);                                            \
    _Pragma("unroll")                                                      \
    for (int kk = 0; kk < 4; kk++) {                                       \
      int c = tc * 4 + kk;                                                 \
      B[2 * kk]     = Bq[(c * 4 + nb) * 64 + lane];                        \
      B[2 * kk + 1] = Bq[(c * 4 + nb + 1) * 64 + lane]; } }
#define H_STA(buf, ra)                                                     \
  { _Pragma("unroll")                                                      \
    for (int p = 0; p < 2; p++) *(uint4*)&Hs[buf][sph[p]] = ra[p]; }
#define H_CMP(buf, B)                                                      \
  { _Pragma("unroll")                                                      \
    for (int kk = 0; kk < 4; kk++) {                                       \
      uint4 af = *(const uint4*)&Hs[buf][(mt * 16 + lrow) * 128 +          \
                                         (((kk * 4 + quad) ^ lrow) & 15) * 8]; \
      acc[0] = bmm(af, B[2 * kk], acc[0]);                                 \
      acc[1] = bmm(af, B[2 * kk + 1], acc[1]); } }

  H_LDA(rAe, 0); H_LDB(B0, 0);
  H_LDA(rAo, 1);
  H_STA(0, rAe);
  H_LDB(B1, 1);
  H_LDA(rAe, 2);
  __syncthreads();

  for (int t = 0; t < 8; t += 2) {
    H_STA(1, rAo);
    H_LDA(rAo, t + 3);
    H_CMP(0, B0);
    H_LDB(B0, t + 2);
    __syncthreads();
    H_STA(0, rAe);
    H_LDA(rAe, t + 4);
    H_CMP(1, B1);
    H_LDB(B1, t + 3);
    __syncthreads();
  }
  H_CMP(0, B0);                                   // tile 8
#undef H_LDA
#undef H_LDB
#undef H_STA
#undef H_CMP

#pragma unroll
  for (int ntl = 0; ntl < 2; ntl++) {
    int col = (nb + ntl) * 16 + lrow;
    float bv = bias1[col];
#pragma unroll
    for (int j = 0; j < 4; j++) {
      int r = m0 + mt * 16 + quad * 4 + j;
      if (r < NN)
        hb[(size_t)r * D2 + col] = f2bf(fmaxf(acc[ntl][j] + bv, 0.f));
    }
  }
}

// ---------------------------------------------------------------------------
// out_v4: out = [hb|A2b](K=576) @ Wc2 + bias2
// ---------------------------------------------------------------------------
__global__ __launch_bounds__(128) void out_v4(
    const unsigned short* __restrict__ hb, const unsigned short* __restrict__ A2b,
    const unsigned short* __restrict__ Wf, const float* __restrict__ bias2,
    float* __restrict__ out) {
  __shared__ unsigned short Os[2][32 * 64];
  const int tid = threadIdx.x;
  const int wv = tid >> 6, lane = tid & 63;
  const int lrow = lane & 15, quad = lane >> 4;
  const int m0 = blockIdx.x * 32;

  int rgr[2], su4[2], sph[2];
#pragma unroll
  for (int p = 0; p < 2; p++) {
    int idx = tid + p * 128;
    int r = idx >> 3, u = idx & 7;
    int g = m0 + r;
    rgr[p] = g < NN ? g : NN - 1;
    su4[p] = u;
    sph[p] = r * 64 + ((u ^ (r & 7)) & 7) * 8;
  }

  const uint4* Bq = (const uint4*)Wf;
  uint4 rAe[2], rAo[2];
  uint4 B0[4], B1[4];
  float4e acc[2];
#pragma unroll
  for (int i = 0; i < 2; i++) {
    acc[i][0] = 0.f; acc[i][1] = 0.f; acc[i][2] = 0.f; acc[i][3] = 0.f;
  }

#define O_LDA(ra, t)                                                       \
  { int tc = (t) > 8 ? 8 : (t);                                            \
    _Pragma("unroll")                                                      \
    for (int p = 0; p < 2; p++) {                                          \
      const unsigned short* sp = (tc == 0)                                 \
          ? (hb + (size_t)rgr[p] * D2 + su4[p] * 8)                        \
          : (A2b + (size_t)rgr[p] * 512 + (tc - 1) * 64 + su4[p] * 8);     \
      ra[p] = *(const uint4*)sp; } }
#define O_LDB(B, t)                                                        \
  { int tc = (t) > 8 ? 8 : (t);                                            \
    _Pragma("unroll")                                                      \
    for (int kk = 0; kk < 2; kk++) {                                       \
      int c = tc * 2 + kk;                                                 \
      B[2 * kk]     = Bq[(c * 2) * 64 + lane];                             \
      B[2 * kk + 1] = Bq[(c * 2 + 1) * 64 + lane]; } }
#define O_STA(buf, ra)                                                     \
  { _Pragma("unroll")                                                      \
    for (int p = 0; p < 2; p++) *(uint4*)&Os[buf][sph[p]] = ra[p]; }
#define O_CMP(buf, B)                                                      \
  { _Pragma("unroll")                                                      \
    for (int kk = 0; kk < 2; kk++) {                                       \
      uint4 af = *(const uint4*)&Os[buf][(wv * 16 + lrow) * 64 +           \
                                         (((kk * 4 + quad) ^ lrow) & 7) * 8]; \
      acc[0] = bmm(af, B[2 * kk], acc[0]);                                 \
      acc[1] = bmm(af, B[2 * kk + 1], acc[1]); } }

  O_LDA(rAe, 0); O_LDB(B0, 0);
  O_LDA(rAo, 1);
  O_STA(0, rAe);
  O_LDB(B1, 1);
  O_LDA(rAe, 2);
  __syncthreads();

  for (int t = 0; t < 8; t += 2) {
    O_STA(1, rAo);
    O_LDA(rAo, t + 3);
    O_CMP(0, B0);
    O_LDB(B0, t + 2);
    __syncthreads();
    O_STA(0, rAe);
    O_LDA(rAe, t + 4);
    O_CMP(1, B1);
    O_LDB(B1, t + 3);
    __syncthreads();
  }
  O_CMP(0, B0);                                   // tile 8
#undef O_LDA
#undef O_LDB
#undef O_STA
#undef O_CMP

#pragma unroll
  for (int ntl = 0; ntl < 2; ntl++) {
    int col = ntl * 16 + lrow;
    if (col < D3) {
      float bv = bias2[col];
#pragma unroll
      for (int j = 0; j < 4; j++) {
        int r = m0 + wv * 16 + quad * 4 + j;
        if (r < NN)
          out[(size_t)r * D3 + col] = acc[ntl][j] + bv;
      }
    }
  }
}

// ---------------------------------------------------------------------------
extern "C" void kernel_launch(void* const* d_in, const int* in_sizes, int n_in,
                              void* d_out, int out_size, void* d_ws,
                              size_t ws_size, hipStream_t stream) {
  const float* x_drug = (const float*)d_in[0];
  const float* drug_w = (const float*)d_in[1];
  const int*   ei     = (const int*)d_in[2];
  const float* basis1 = (const float*)d_in[3];
  const float* comp1  = (const float*)d_in[4];
  const float* root1  = (const float*)d_in[5];
  const float* bias1  = (const float*)d_in[6];
  const float* basis2 = (const float*)d_in[7];
  const float* comp2  = (const float*)d_in[8];
  const float* root2  = (const float*)d_in[9];
  const float* bias2  = (const float*)d_in[10];
  float* out = (float*)d_out;

  float* ws = (float*)d_ws;
  int*   deg  = (int*)ws;                          // 1,000,000
  int*   cnt  = deg + 1000000;                     // 10,016
  int*   off  = cnt + 10016;                       // 10,016
  int*   cur  = off + 10016;                       // 10,016
  int2*  re   = (int2*)(cur + 10016);              // 500,000 int2 (1M ints)
  unsigned short* xb   = (unsigned short*)((int*)re + 1000000);    // 640,000 f
  unsigned short* hb   = (unsigned short*)((float*)xb + 640000);   // 320,000 f
  unsigned short* Bfw  = (unsigned short*)((float*)hb + 320000);   // 131,072 f
  unsigned short* Wf1  = (unsigned short*)((float*)Bfw + 131072);  // 36,864 f
  unsigned short* Wf2  = (unsigned short*)((float*)Wf1 + 36864);   // 9,216 f
  float* R1 = (float*)Wf2 + 9216;                  // aggregation buffers
  unsigned short* A1b = (unsigned short*)R1;       // 10,000 x 1024 bf16
  unsigned short* A2b = (unsigned short*)R1;       // aliases A1b (after hlayer)

  hipMemsetAsync(deg, 0, (size_t)1000000 * 4, stream);

  // CSR build + weight prep (fused first pass)
  prep_kernel<<<(NE + W0_SZ + W1_SZ + W2_SZ + 255) / 256, 256, 0, stream>>>(
      ei, deg, drug_w, Bfw, root1, basis1, Wf1, root2, basis2, Wf2);

  // gemm0 (needs Bfw) overlapped with cnt (needs deg) -- both from prep
  gemm0cnt<<<313 + 40, 256, 0, stream>>>(x_drug, Bfw, xb, deg, cnt);

  scan_kernel<<<1, 1024, 0, stream>>>(cnt, off, cur);
  scatter_kernel<<<(NE + 255) / 256, 256, 0, stream>>>(ei, deg, cur, re);

  // layer 1
  agg1e_kernel<<<(NN + 3) / 4, 256, 0, stream>>>(xb, off, re, comp1, A1b);
  hlayer_v4<<<(NN + 31) / 32, 256, 0, stream>>>(xb, A1b, Wf1, bias1, hb);

  // layer 2
  agg2e_kernel<<<(NN + 3) / 4, 256, 0, stream>>>(hb, off, re, comp2, A2b);
  out_v4<<<(NN + 31) / 32, 128, 0, stream>>>(hb, A2b, Wf2, bias2, out);
}